// Round 1
// baseline (1249.652 us; speedup 1.0000x reference)
//
#include <hip/hip_runtime.h>
#include <hip/hip_bf16.h>

#define D_MODEL 1024
#define D_STATE 16
#define L_SEQ 2048
#define B_SZ 4
#define M_ROWS (B_SZ * L_SEQ)   // 8192

typedef __attribute__((ext_vector_type(8))) short short8;
typedef __attribute__((ext_vector_type(4))) float f32x4;

static __device__ __forceinline__ unsigned short f2bf(float f) {
    unsigned int u = __float_as_uint(f);
    unsigned int r = (u + 0x7FFFu + ((u >> 16) & 1u)) >> 16;   // RNE
    return (unsigned short)r;
}
static __device__ __forceinline__ float bf2f(unsigned short u) {
    return __uint_as_float(((unsigned int)u) << 16);
}

// ---------------- convert fp32 -> bf16 (weights) ----------------
__global__ void conv_bf16_kernel(const float* __restrict__ src,
                                 unsigned short* __restrict__ dst, int n4) {
    int i = blockIdx.x * blockDim.x + threadIdx.x;
    if (i < n4) {
        float4 v = ((const float4*)src)[i];
        ushort4 o;
        o.x = f2bf(v.x); o.y = f2bf(v.y); o.z = f2bf(v.z); o.w = f2bf(v.w);
        ((ushort4*)dst)[i] = o;
    }
}

// ---------------- LayerNorm: x (8192 x 1024) -> xn bf16 ----------------
__global__ __launch_bounds__(256) void ln_kernel(const float* __restrict__ x,
                                                 const float* __restrict__ g,
                                                 const float* __restrict__ b,
                                                 unsigned short* __restrict__ xn) {
    int row = blockIdx.x;
    int t = threadIdx.x;
    const float4* xr = (const float4*)(x + (size_t)row * D_MODEL);
    float4 v = xr[t];
    float s  = v.x + v.y + v.z + v.w;
    float ss = v.x * v.x + v.y * v.y + v.z * v.z + v.w * v.w;
    #pragma unroll
    for (int o = 32; o > 0; o >>= 1) {
        s  += __shfl_down(s,  o);
        ss += __shfl_down(ss, o);
    }
    __shared__ float sbuf[8];
    int wid = t >> 6;
    if ((t & 63) == 0) { sbuf[wid] = s; sbuf[4 + wid] = ss; }
    __syncthreads();
    float S  = sbuf[0] + sbuf[1] + sbuf[2] + sbuf[3];
    float SS = sbuf[4] + sbuf[5] + sbuf[6] + sbuf[7];
    float mu  = S * (1.0f / D_MODEL);
    float var = SS * (1.0f / D_MODEL) - mu * mu;
    float inv = rsqrtf(var + 1e-5f);
    float4 gv = ((const float4*)g)[t];
    float4 bv = ((const float4*)b)[t];
    ushort4 o;
    o.x = f2bf((v.x - mu) * inv * gv.x + bv.x);
    o.y = f2bf((v.y - mu) * inv * gv.y + bv.y);
    o.z = f2bf((v.z - mu) * inv * gv.z + bv.z);
    o.w = f2bf((v.w - mu) * inv * gv.w + bv.w);
    ((ushort4*)(xn + (size_t)row * D_MODEL))[t] = o;
}

// ---------------- GEMM (NT, bf16 MFMA, direct-from-global) ----------------
// D[m][n] = sum_k A[m][k] * Bt[n][k] + bias[n]
// MODE 1: n<1024 -> out_f (u fp32);  n>=1024 -> silu -> out_bf (z bf16)
// MODE 2: out_f = clip(D + resid, -10, 10) (fp32)
template<int MODE>
__global__ __launch_bounds__(256) void gemm_kernel(const unsigned short* __restrict__ A,
                                                   const unsigned short* __restrict__ Bt,
                                                   const float* __restrict__ bias,
                                                   float* __restrict__ out_f,
                                                   unsigned short* __restrict__ out_bf,
                                                   const float* __restrict__ resid,
                                                   int K) {
    int lane = threadIdx.x & 63;
    int wave = threadIdx.x >> 6;
    int wm = wave >> 1, wn = wave & 1;
    int m0 = blockIdx.y * 128 + wm * 64;
    int n0 = blockIdx.x * 128 + wn * 64;
    int row = lane & 15;      // A/B operand: index within 16 (m or n)
    int quad = lane >> 4;     // k-quad

    const unsigned short* Ap[4];
    const unsigned short* Bp[4];
    #pragma unroll
    for (int i = 0; i < 4; i++) Ap[i] = A + (size_t)(m0 + i * 16 + row) * K + quad * 8;
    #pragma unroll
    for (int j = 0; j < 4; j++) Bp[j] = Bt + (size_t)(n0 + j * 16 + row) * K + quad * 8;

    f32x4 acc[4][4] = {};

    for (int kk = 0; kk < K; kk += 32) {
        short8 a[4], b[4];
        #pragma unroll
        for (int i = 0; i < 4; i++) a[i] = *(const short8*)(Ap[i] + kk);
        #pragma unroll
        for (int j = 0; j < 4; j++) b[j] = *(const short8*)(Bp[j] + kk);
        #pragma unroll
        for (int i = 0; i < 4; i++)
            #pragma unroll
            for (int j = 0; j < 4; j++)
                acc[i][j] = __builtin_amdgcn_mfma_f32_16x16x32_bf16(a[i], b[j], acc[i][j], 0, 0, 0);
    }

    // epilogue: C/D layout col = lane&15, row = quad*4 + reg
    int col = row;
    #pragma unroll
    for (int i = 0; i < 4; i++) {
        #pragma unroll
        for (int j = 0; j < 4; j++) {
            int n = n0 + j * 16 + col;
            float bs = bias[n];
            #pragma unroll
            for (int r = 0; r < 4; r++) {
                int m = m0 + i * 16 + quad * 4 + r;
                float v = acc[i][j][r] + bs;
                if (MODE == 1) {
                    if (n < D_MODEL) {
                        out_f[(size_t)m * D_MODEL + n] = v;
                    } else {
                        float sv = v / (1.0f + __expf(-v));
                        out_bf[(size_t)m * D_MODEL + (n - D_MODEL)] = f2bf(sv);
                    }
                } else {
                    float y = v + resid[(size_t)m * D_MODEL + n];
                    y = fminf(10.0f, fmaxf(-10.0f, y));
                    out_f[(size_t)m * D_MODEL + n] = y;
                }
            }
        }
    }
}

// ---------------- SSM scan fused with y*silu(z) ----------------
// thread per (b, d, n): 65536 threads. 16-lane butterfly per step.
__global__ __launch_bounds__(256) void scan_kernel(const float* __restrict__ u,
                                                   const unsigned short* __restrict__ zs,
                                                   const float* __restrict__ A_log,
                                                   const float* __restrict__ Bp,
                                                   const float* __restrict__ Cp,
                                                   const float* __restrict__ log_dt,
                                                   unsigned short* __restrict__ yz) {
    int idx = blockIdx.x * 256 + threadIdx.x;
    int n = idx & 15;
    int d = (idx >> 4) & (D_MODEL - 1);
    int b = idx >> 14;

    float dt = fminf(1.0f, fmaxf(1e-4f, __expf(log_dt[d])));
    float Abar = __expf(-__expf(A_log[d * D_STATE + n]) * dt);
    Abar = fminf(1.0f - 1e-8f, fmaxf(1e-8f, Abar));
    float cb = Cp[d * D_STATE + n] * Bp[d * D_STATE + n] * dt;

    const float* up = u + (size_t)b * L_SEQ * D_MODEL + d;
    const unsigned short* zp = zs + (size_t)b * L_SEQ * D_MODEL + d;
    unsigned short* yp = yz + (size_t)b * L_SEQ * D_MODEL + d;

    float s = 0.0f;
    bool leader = (n == 0);
    float uv = up[0];
    for (int t = 0; t < L_SEQ; t++) {
        float uv_next = (t + 1 < L_SEQ) ? up[(size_t)(t + 1) * D_MODEL] : 0.0f;
        s = fmaf(Abar, s, uv);
        float p = cb * s;
        p += __shfl_xor(p, 1);
        p += __shfl_xor(p, 2);
        p += __shfl_xor(p, 4);
        p += __shfl_xor(p, 8);
        if (leader) {
            float zv = bf2f(zp[(size_t)t * D_MODEL]);
            yp[(size_t)t * D_MODEL] = f2bf(p * zv);
        }
        uv = uv_next;
    }
}

extern "C" void kernel_launch(void* const* d_in, const int* in_sizes, int n_in,
                              void* d_out, int out_size, void* d_ws, size_t ws_size,
                              hipStream_t stream) {
    const float* x       = (const float*)d_in[0];
    const float* A_log   = (const float*)d_in[1];
    const float* B_param = (const float*)d_in[2];
    const float* C_param = (const float*)d_in[3];
    const float* log_dt  = (const float*)d_in[4];
    const float* in_w    = (const float*)d_in[5];
    const float* in_b    = (const float*)d_in[6];
    const float* out_w   = (const float*)d_in[7];
    const float* out_b   = (const float*)d_in[8];
    const float* ln_g    = (const float*)d_in[9];
    const float* ln_b    = (const float*)d_in[10];
    float* out = (float*)d_out;

    char* ws = (char*)d_ws;
    size_t off = 0;
    unsigned short* xn = (unsigned short*)(ws + off); off += (size_t)M_ROWS * D_MODEL * 2;        // 16 MB
    unsigned short* w1 = (unsigned short*)(ws + off); off += (size_t)2 * D_MODEL * D_MODEL * 2;   // 4 MB
    float*          u  = (float*)(ws + off);          off += (size_t)M_ROWS * D_MODEL * 4;        // 32 MB
    unsigned short* zs = (unsigned short*)(ws + off); off += (size_t)M_ROWS * D_MODEL * 2;        // 16 MB
    unsigned short* yz = (unsigned short*)(ws + off); off += (size_t)M_ROWS * D_MODEL * 2;        // 16 MB
    unsigned short* w2 = (unsigned short*)(ws + off); off += (size_t)D_MODEL * D_MODEL * 2;       // 2 MB

    // weights -> bf16
    {
        int n4 = 2 * D_MODEL * D_MODEL / 4;
        conv_bf16_kernel<<<(n4 + 255) / 256, 256, 0, stream>>>(in_w, w1, n4);
    }
    {
        int n4 = D_MODEL * D_MODEL / 4;
        conv_bf16_kernel<<<(n4 + 255) / 256, 256, 0, stream>>>(out_w, w2, n4);
    }

    // layernorm
    ln_kernel<<<M_ROWS, 256, 0, stream>>>(x, ln_g, ln_b, xn);

    // GEMM1: (8192x1024) @ (2048x1024)^T -> u fp32 / silu(z) bf16
    gemm_kernel<1><<<dim3(2 * D_MODEL / 128, M_ROWS / 128), 256, 0, stream>>>(
        xn, w1, in_b, u, zs, nullptr, D_MODEL);

    // SSM scan fused with z-multiply
    scan_kernel<<<(B_SZ * D_MODEL * D_STATE) / 256, 256, 0, stream>>>(
        u, zs, A_log, B_param, C_param, log_dt, yz);

    // GEMM2: (8192x1024) @ (1024x1024)^T + resid, clip
    gemm_kernel<2><<<dim3(D_MODEL / 128, M_ROWS / 128), 256, 0, stream>>>(
        yz, w2, out_b, out, nullptr, x, D_MODEL);
}

// Round 2
// 332.763 us; speedup vs baseline: 3.7554x; 3.7554x over previous
//
#include <hip/hip_runtime.h>
#include <hip/hip_bf16.h>

#define D_MODEL 1024
#define D_STATE 16
#define L_SEQ 2048
#define B_SZ 4
#define M_ROWS (B_SZ * L_SEQ)   // 8192
#define N_CHUNK 32               // chunks per sequence
#define C_LEN 64                 // timesteps per chunk (32*64 = 2048)

typedef __attribute__((ext_vector_type(8))) short short8;
typedef __attribute__((ext_vector_type(4))) float f32x4;

static __device__ __forceinline__ unsigned short f2bf(float f) {
    unsigned int u = __float_as_uint(f);
    unsigned int r = (u + 0x7FFFu + ((u >> 16) & 1u)) >> 16;   // RNE
    return (unsigned short)r;
}
static __device__ __forceinline__ float bf2f(unsigned short u) {
    return __uint_as_float(((unsigned int)u) << 16);
}

// ---------------- convert fp32 -> bf16 (weights) ----------------
__global__ void conv_bf16_kernel(const float* __restrict__ src,
                                 unsigned short* __restrict__ dst, int n4) {
    int i = blockIdx.x * blockDim.x + threadIdx.x;
    if (i < n4) {
        float4 v = ((const float4*)src)[i];
        ushort4 o;
        o.x = f2bf(v.x); o.y = f2bf(v.y); o.z = f2bf(v.z); o.w = f2bf(v.w);
        ((ushort4*)dst)[i] = o;
    }
}

// ---------------- LayerNorm: x (8192 x 1024) -> xn bf16 ----------------
__global__ __launch_bounds__(256) void ln_kernel(const float* __restrict__ x,
                                                 const float* __restrict__ g,
                                                 const float* __restrict__ b,
                                                 unsigned short* __restrict__ xn) {
    int row = blockIdx.x;
    int t = threadIdx.x;
    const float4* xr = (const float4*)(x + (size_t)row * D_MODEL);
    float4 v = xr[t];
    float s  = v.x + v.y + v.z + v.w;
    float ss = v.x * v.x + v.y * v.y + v.z * v.z + v.w * v.w;
    #pragma unroll
    for (int o = 32; o > 0; o >>= 1) {
        s  += __shfl_down(s,  o);
        ss += __shfl_down(ss, o);
    }
    __shared__ float sbuf[8];
    int wid = t >> 6;
    if ((t & 63) == 0) { sbuf[wid] = s; sbuf[4 + wid] = ss; }
    __syncthreads();
    float S  = sbuf[0] + sbuf[1] + sbuf[2] + sbuf[3];
    float SS = sbuf[4] + sbuf[5] + sbuf[6] + sbuf[7];
    float mu  = S * (1.0f / D_MODEL);
    float var = SS * (1.0f / D_MODEL) - mu * mu;
    float inv = rsqrtf(var + 1e-5f);
    float4 gv = ((const float4*)g)[t];
    float4 bv = ((const float4*)b)[t];
    ushort4 o;
    o.x = f2bf((v.x - mu) * inv * gv.x + bv.x);
    o.y = f2bf((v.y - mu) * inv * gv.y + bv.y);
    o.z = f2bf((v.z - mu) * inv * gv.z + bv.z);
    o.w = f2bf((v.w - mu) * inv * gv.w + bv.w);
    ((ushort4*)(xn + (size_t)row * D_MODEL))[t] = o;
}

// ---------------- GEMM (NT, bf16 MFMA, direct-from-global) ----------------
template<int MODE>
__global__ __launch_bounds__(256) void gemm_kernel(const unsigned short* __restrict__ A,
                                                   const unsigned short* __restrict__ Bt,
                                                   const float* __restrict__ bias,
                                                   float* __restrict__ out_f,
                                                   unsigned short* __restrict__ out_bf,
                                                   const float* __restrict__ resid,
                                                   int K) {
    int lane = threadIdx.x & 63;
    int wave = threadIdx.x >> 6;
    int wm = wave >> 1, wn = wave & 1;
    int m0 = blockIdx.y * 128 + wm * 64;
    int n0 = blockIdx.x * 128 + wn * 64;
    int row = lane & 15;
    int quad = lane >> 4;

    const unsigned short* Ap[4];
    const unsigned short* Bp[4];
    #pragma unroll
    for (int i = 0; i < 4; i++) Ap[i] = A + (size_t)(m0 + i * 16 + row) * K + quad * 8;
    #pragma unroll
    for (int j = 0; j < 4; j++) Bp[j] = Bt + (size_t)(n0 + j * 16 + row) * K + quad * 8;

    f32x4 acc[4][4] = {};

    for (int kk = 0; kk < K; kk += 32) {
        short8 a[4], b[4];
        #pragma unroll
        for (int i = 0; i < 4; i++) a[i] = *(const short8*)(Ap[i] + kk);
        #pragma unroll
        for (int j = 0; j < 4; j++) b[j] = *(const short8*)(Bp[j] + kk);
        #pragma unroll
        for (int i = 0; i < 4; i++)
            #pragma unroll
            for (int j = 0; j < 4; j++)
                acc[i][j] = __builtin_amdgcn_mfma_f32_16x16x32_bf16(a[i], b[j], acc[i][j], 0, 0, 0);
    }

    int col = row;
    #pragma unroll
    for (int i = 0; i < 4; i++) {
        #pragma unroll
        for (int j = 0; j < 4; j++) {
            int n = n0 + j * 16 + col;
            float bs = bias[n];
            #pragma unroll
            for (int r = 0; r < 4; r++) {
                int m = m0 + i * 16 + quad * 4 + r;
                float v = acc[i][j][r] + bs;
                if (MODE == 1) {
                    if (n < D_MODEL) {
                        out_f[(size_t)m * D_MODEL + n] = v;
                    } else {
                        float sv = v / (1.0f + __expf(-v));
                        out_bf[(size_t)m * D_MODEL + (n - D_MODEL)] = f2bf(sv);
                    }
                } else {
                    float y = v + resid[(size_t)m * D_MODEL + n];
                    y = fminf(10.0f, fmaxf(-10.0f, y));
                    out_f[(size_t)m * D_MODEL + n] = y;
                }
            }
        }
    }
}

// ---------------- chunked SSM scan ----------------
// Shared per-thread param setup: 16 states, Abar/cb in registers.
static __device__ __forceinline__ void load_params(const float* __restrict__ A_log,
                                                   const float* __restrict__ log_dt,
                                                   int d, float* ab, float& dt_out) {
    float dt = fminf(1.0f, fmaxf(1e-4f, __expf(log_dt[d])));
    #pragma unroll
    for (int n = 0; n < D_STATE; n++) {
        float a = __expf(-__expf(A_log[d * D_STATE + n]) * dt);
        ab[n] = fminf(1.0f - 1e-8f, fmaxf(1e-8f, a));
    }
    dt_out = dt;
}

// pass1: zero-init local scan of each chunk; writes chunk-final states.
// thread id = ((b*N_CHUNK + c) * D_MODEL + d)
__global__ __launch_bounds__(256) void scan1_kernel(const float* __restrict__ u,
                                                    const float* __restrict__ A_log,
                                                    const float* __restrict__ log_dt,
                                                    float* __restrict__ s_local) {
    int gid = blockIdx.x * 256 + threadIdx.x;
    int d = gid & (D_MODEL - 1);
    int c = (gid >> 10) & (N_CHUNK - 1);
    int b = gid >> 15;

    float ab[D_STATE], dt;
    load_params(A_log, log_dt, d, ab, dt);

    float s[D_STATE];
    #pragma unroll
    for (int n = 0; n < D_STATE; n++) s[n] = 0.0f;

    const float* up = u + ((size_t)(b * L_SEQ + c * C_LEN)) * D_MODEL + d;
    for (int t = 0; t < C_LEN; t++) {
        float uv = up[(size_t)t * D_MODEL];
        #pragma unroll
        for (int n = 0; n < D_STATE; n++) s[n] = fmaf(ab[n], s[n], uv);
    }
    float* sl = s_local + ((size_t)(b * N_CHUNK + c) * D_STATE) * D_MODEL + d;
    #pragma unroll
    for (int n = 0; n < D_STATE; n++) sl[(size_t)n * D_MODEL] = s[n];
}

// combine: sequential prefix over chunks. thread id = ((b*D_STATE + n) * D_MODEL + d)
__global__ __launch_bounds__(256) void scan_combine_kernel(const float* __restrict__ s_local,
                                                           const float* __restrict__ A_log,
                                                           const float* __restrict__ log_dt,
                                                           float* __restrict__ s_init) {
    int gid = blockIdx.x * 256 + threadIdx.x;
    int d = gid & (D_MODEL - 1);
    int n = (gid >> 10) & (D_STATE - 1);
    int b = gid >> 14;

    float dt = fminf(1.0f, fmaxf(1e-4f, __expf(log_dt[d])));
    float a = __expf(-__expf(A_log[d * D_STATE + n]) * dt);
    a = fminf(1.0f - 1e-8f, fmaxf(1e-8f, a));
    // a^64 by repeated squaring
    float aP = a;
    #pragma unroll
    for (int q = 0; q < 6; q++) aP = aP * aP;

    float s = 0.0f;
    size_t stride_c = (size_t)D_STATE * D_MODEL;
    const float* sl = s_local + ((size_t)b * N_CHUNK * D_STATE + n) * D_MODEL + d;
    float* si = s_init + ((size_t)b * N_CHUNK * D_STATE + n) * D_MODEL + d;
    si[0] = 0.0f;
    for (int c = 1; c < N_CHUNK; c++) {
        s = fmaf(aP, s, sl[(size_t)(c - 1) * stride_c]);
        si[(size_t)c * stride_c] = s;
    }
}

// pass2: rescan with correct init; fuse y = sum_n cb_n s_n, y *= silu(z); bf16 out.
__global__ __launch_bounds__(256) void scan2_kernel(const float* __restrict__ u,
                                                    const unsigned short* __restrict__ zs,
                                                    const float* __restrict__ A_log,
                                                    const float* __restrict__ Bp,
                                                    const float* __restrict__ Cp,
                                                    const float* __restrict__ log_dt,
                                                    const float* __restrict__ s_init,
                                                    unsigned short* __restrict__ yz) {
    int gid = blockIdx.x * 256 + threadIdx.x;
    int d = gid & (D_MODEL - 1);
    int c = (gid >> 10) & (N_CHUNK - 1);
    int b = gid >> 15;

    float ab[D_STATE], dt;
    load_params(A_log, log_dt, d, ab, dt);
    float cb[D_STATE];
    #pragma unroll
    for (int n = 0; n < D_STATE; n++)
        cb[n] = Cp[d * D_STATE + n] * Bp[d * D_STATE + n] * dt;

    float s[D_STATE];
    const float* si = s_init + ((size_t)(b * N_CHUNK + c) * D_STATE) * D_MODEL + d;
    #pragma unroll
    for (int n = 0; n < D_STATE; n++) s[n] = si[(size_t)n * D_MODEL];

    size_t m0 = (size_t)(b * L_SEQ + c * C_LEN);
    const float* up = u + m0 * D_MODEL + d;
    const unsigned short* zp = zs + m0 * D_MODEL + d;
    unsigned short* yp = yz + m0 * D_MODEL + d;

    for (int t = 0; t < C_LEN; t++) {
        float uv = up[(size_t)t * D_MODEL];
        #pragma unroll
        for (int n = 0; n < D_STATE; n++) s[n] = fmaf(ab[n], s[n], uv);
        float y = 0.0f;
        #pragma unroll
        for (int n = 0; n < D_STATE; n++) y = fmaf(cb[n], s[n], y);
        float zv = bf2f(zp[(size_t)t * D_MODEL]);
        yp[(size_t)t * D_MODEL] = f2bf(y * zv);
    }
}

extern "C" void kernel_launch(void* const* d_in, const int* in_sizes, int n_in,
                              void* d_out, int out_size, void* d_ws, size_t ws_size,
                              hipStream_t stream) {
    const float* x       = (const float*)d_in[0];
    const float* A_log   = (const float*)d_in[1];
    const float* B_param = (const float*)d_in[2];
    const float* C_param = (const float*)d_in[3];
    const float* log_dt  = (const float*)d_in[4];
    const float* in_w    = (const float*)d_in[5];
    const float* in_b    = (const float*)d_in[6];
    const float* out_w   = (const float*)d_in[7];
    const float* out_b   = (const float*)d_in[8];
    const float* ln_g    = (const float*)d_in[9];
    const float* ln_b    = (const float*)d_in[10];
    float* out = (float*)d_out;

    char* ws = (char*)d_ws;
    size_t off = 0;
    unsigned short* xn = (unsigned short*)(ws + off); off += (size_t)M_ROWS * D_MODEL * 2;        // 16 MB
    unsigned short* w1 = (unsigned short*)(ws + off); off += (size_t)2 * D_MODEL * D_MODEL * 2;   // 4 MB
    float*          u  = (float*)(ws + off);          off += (size_t)M_ROWS * D_MODEL * 4;        // 32 MB
    unsigned short* zs = (unsigned short*)(ws + off); off += (size_t)M_ROWS * D_MODEL * 2;        // 16 MB
    unsigned short* yz = (unsigned short*)(ws + off); off += (size_t)M_ROWS * D_MODEL * 2;        // 16 MB
    unsigned short* w2 = (unsigned short*)(ws + off); off += (size_t)D_MODEL * D_MODEL * 2;       // 2 MB
    float* s_local = (float*)(ws + off); off += (size_t)B_SZ * N_CHUNK * D_STATE * D_MODEL * 4;   // 8 MB
    float* s_init  = (float*)(ws + off); off += (size_t)B_SZ * N_CHUNK * D_STATE * D_MODEL * 4;   // 8 MB

    // weights -> bf16
    {
        int n4 = 2 * D_MODEL * D_MODEL / 4;
        conv_bf16_kernel<<<(n4 + 255) / 256, 256, 0, stream>>>(in_w, w1, n4);
    }
    {
        int n4 = D_MODEL * D_MODEL / 4;
        conv_bf16_kernel<<<(n4 + 255) / 256, 256, 0, stream>>>(out_w, w2, n4);
    }

    // layernorm
    ln_kernel<<<M_ROWS, 256, 0, stream>>>(x, ln_g, ln_b, xn);

    // GEMM1: (8192x1024) @ (2048x1024)^T -> u fp32 / silu(z) bf16
    gemm_kernel<1><<<dim3(2 * D_MODEL / 128, M_ROWS / 128), 256, 0, stream>>>(
        xn, w1, in_b, u, zs, nullptr, D_MODEL);

    // chunked SSM scan
    scan1_kernel<<<(B_SZ * N_CHUNK * D_MODEL) / 256, 256, 0, stream>>>(u, A_log, log_dt, s_local);
    scan_combine_kernel<<<(B_SZ * D_STATE * D_MODEL) / 256, 256, 0, stream>>>(s_local, A_log, log_dt, s_init);
    scan2_kernel<<<(B_SZ * N_CHUNK * D_MODEL) / 256, 256, 0, stream>>>(
        u, zs, A_log, B_param, C_param, log_dt, s_init, yz);

    // GEMM2: (8192x1024) @ (1024x1024)^T + resid, clip
    gemm_kernel<2><<<dim3(D_MODEL / 128, M_ROWS / 128), 256, 0, stream>>>(
        yz, w2, out_b, out, nullptr, x, D_MODEL);
}

// Round 3
// 243.785 us; speedup vs baseline: 5.1260x; 1.3650x over previous
//
#include <hip/hip_runtime.h>
#include <hip/hip_bf16.h>

#define D_MODEL 1024
#define D_STATE 16
#define L_SEQ 2048
#define B_SZ 4
#define M_ROWS (B_SZ * L_SEQ)   // 8192
#define N_CHUNK 32               // chunks per sequence
#define C_LEN 64                 // timesteps per chunk (32*64 = 2048)

typedef __attribute__((ext_vector_type(8))) short short8;
typedef __attribute__((ext_vector_type(4))) float f32x4;
typedef unsigned int u32;
#define GLOBAL_AS __attribute__((address_space(1)))
#define LDS_AS __attribute__((address_space(3)))

static __device__ __forceinline__ unsigned short f2bf(float f) {
    unsigned int u = __float_as_uint(f);
    unsigned int r = (u + 0x7FFFu + ((u >> 16) & 1u)) >> 16;   // RNE
    return (unsigned short)r;
}
static __device__ __forceinline__ float bf2f(unsigned short u) {
    return __uint_as_float(((unsigned int)u) << 16);
}

// ---------------- convert fp32 -> bf16 (weights) ----------------
__global__ void conv_bf16_kernel(const float* __restrict__ src,
                                 unsigned short* __restrict__ dst, int n4) {
    int i = blockIdx.x * blockDim.x + threadIdx.x;
    if (i < n4) {
        float4 v = ((const float4*)src)[i];
        ushort4 o;
        o.x = f2bf(v.x); o.y = f2bf(v.y); o.z = f2bf(v.z); o.w = f2bf(v.w);
        ((ushort4*)dst)[i] = o;
    }
}

// ---------------- LayerNorm: x (8192 x 1024) -> xn bf16 ----------------
__global__ __launch_bounds__(256) void ln_kernel(const float* __restrict__ x,
                                                 const float* __restrict__ g,
                                                 const float* __restrict__ b,
                                                 unsigned short* __restrict__ xn) {
    int row = blockIdx.x;
    int t = threadIdx.x;
    const float4* xr = (const float4*)(x + (size_t)row * D_MODEL);
    float4 v = xr[t];
    float s  = v.x + v.y + v.z + v.w;
    float ss = v.x * v.x + v.y * v.y + v.z * v.z + v.w * v.w;
    #pragma unroll
    for (int o = 32; o > 0; o >>= 1) {
        s  += __shfl_down(s,  o);
        ss += __shfl_down(ss, o);
    }
    __shared__ float sbuf[8];
    int wid = t >> 6;
    if ((t & 63) == 0) { sbuf[wid] = s; sbuf[4 + wid] = ss; }
    __syncthreads();
    float S  = sbuf[0] + sbuf[1] + sbuf[2] + sbuf[3];
    float SS = sbuf[4] + sbuf[5] + sbuf[6] + sbuf[7];
    float mu  = S * (1.0f / D_MODEL);
    float var = SS * (1.0f / D_MODEL) - mu * mu;
    float inv = rsqrtf(var + 1e-5f);
    float4 gv = ((const float4*)g)[t];
    float4 bv = ((const float4*)b)[t];
    ushort4 o;
    o.x = f2bf((v.x - mu) * inv * gv.x + bv.x);
    o.y = f2bf((v.y - mu) * inv * gv.y + bv.y);
    o.z = f2bf((v.z - mu) * inv * gv.z + bv.z);
    o.w = f2bf((v.w - mu) * inv * gv.w + bv.w);
    ((ushort4*)(xn + (size_t)row * D_MODEL))[t] = o;
}

// ---------------- GEMM (NT, bf16 MFMA, LDS-staged m97 structure) ----------------
// D[m][n] = sum_k A[m][k] * Bt[n][k] + bias[n]
// Block: 256 threads (4 waves, 2x2), tile 128x128, BK=32.
// MODE 1: n<1024 -> out_f (u fp32);  n>=1024 -> silu -> out_bf (z bf16)
// MODE 2: out_f = clip(D + resid, -10, 10) (fp32)
template<int MODE>
__global__ __launch_bounds__(256) void gemm_kernel(const unsigned short* __restrict__ A,
                                                   const unsigned short* __restrict__ Bt,
                                                   const float* __restrict__ bias,
                                                   float* __restrict__ out_f,
                                                   unsigned short* __restrict__ out_bf,
                                                   const float* __restrict__ resid,
                                                   int K) {
    __shared__ unsigned short lA[128 * 32];   // 8 KB, row-major [row][k], unpadded
    __shared__ unsigned short lB[128 * 32];   // 8 KB

    int t = threadIdx.x;
    int lane = t & 63;
    int wave = t >> 6;
    int wm = wave >> 1, wn = wave & 1;
    int m0 = blockIdx.y * 128;
    int n0 = blockIdx.x * 128;
    int row = lane & 15;
    int quad = lane >> 4;

    // staging: thread t covers tile row sr (and sr+64), 8 bf16 at col sc
    int sr = t >> 2;
    int sc = (t & 3) * 8;
    const unsigned short* gA0 = A + (size_t)(m0 + sr) * K + sc;
    const unsigned short* gA1 = A + (size_t)(m0 + 64 + sr) * K + sc;
    const unsigned short* gB0 = Bt + (size_t)(n0 + sr) * K + sc;
    const unsigned short* gB1 = Bt + (size_t)(n0 + 64 + sr) * K + sc;

    f32x4 acc[4][4] = {};

    for (int kk = 0; kk < K; kk += 32) {
        __builtin_amdgcn_global_load_lds((const GLOBAL_AS u32*)(gA0 + kk),
                                         (LDS_AS u32*)&lA[t * 8], 16, 0, 0);
        __builtin_amdgcn_global_load_lds((const GLOBAL_AS u32*)(gA1 + kk),
                                         (LDS_AS u32*)&lA[2048 + t * 8], 16, 0, 0);
        __builtin_amdgcn_global_load_lds((const GLOBAL_AS u32*)(gB0 + kk),
                                         (LDS_AS u32*)&lB[t * 8], 16, 0, 0);
        __builtin_amdgcn_global_load_lds((const GLOBAL_AS u32*)(gB1 + kk),
                                         (LDS_AS u32*)&lB[2048 + t * 8], 16, 0, 0);
        __syncthreads();

        short8 a[4], b[4];
        #pragma unroll
        for (int i = 0; i < 4; i++)
            a[i] = *(const short8*)&lA[(wm * 64 + i * 16 + row) * 32 + quad * 8];
        #pragma unroll
        for (int j = 0; j < 4; j++)
            b[j] = *(const short8*)&lB[(wn * 64 + j * 16 + row) * 32 + quad * 8];
        #pragma unroll
        for (int i = 0; i < 4; i++)
            #pragma unroll
            for (int j = 0; j < 4; j++)
                acc[i][j] = __builtin_amdgcn_mfma_f32_16x16x32_bf16(a[i], b[j], acc[i][j], 0, 0, 0);
        __syncthreads();
    }

    // epilogue: C/D layout col = lane&15, row = quad*4 + reg
    int col = row;
    #pragma unroll
    for (int i = 0; i < 4; i++) {
        #pragma unroll
        for (int j = 0; j < 4; j++) {
            int n = n0 + wn * 64 + j * 16 + col;
            float bs = bias[n];
            #pragma unroll
            for (int r = 0; r < 4; r++) {
                int m = m0 + wm * 64 + i * 16 + quad * 4 + r;
                float v = acc[i][j][r] + bs;
                if (MODE == 1) {
                    if (n < D_MODEL) {
                        out_f[(size_t)m * D_MODEL + n] = v;
                    } else {
                        float sv = v / (1.0f + __expf(-v));
                        out_bf[(size_t)m * D_MODEL + (n - D_MODEL)] = f2bf(sv);
                    }
                } else {
                    float y = v + resid[(size_t)m * D_MODEL + n];
                    y = fminf(10.0f, fmaxf(-10.0f, y));
                    out_f[(size_t)m * D_MODEL + n] = y;
                }
            }
        }
    }
}

// ---------------- chunked SSM scan ----------------
static __device__ __forceinline__ void load_params(const float* __restrict__ A_log,
                                                   const float* __restrict__ log_dt,
                                                   int d, float* ab, float& dt_out) {
    float dt = fminf(1.0f, fmaxf(1e-4f, __expf(log_dt[d])));
    #pragma unroll
    for (int n = 0; n < D_STATE; n++) {
        float a = __expf(-__expf(A_log[d * D_STATE + n]) * dt);
        ab[n] = fminf(1.0f - 1e-8f, fmaxf(1e-8f, a));
    }
    dt_out = dt;
}

// pass1: zero-init local scan of each chunk; writes chunk-final states.
__global__ __launch_bounds__(256) void scan1_kernel(const float* __restrict__ u,
                                                    const float* __restrict__ A_log,
                                                    const float* __restrict__ log_dt,
                                                    float* __restrict__ s_local) {
    int gid = blockIdx.x * 256 + threadIdx.x;
    int d = gid & (D_MODEL - 1);
    int c = (gid >> 10) & (N_CHUNK - 1);
    int b = gid >> 15;

    float ab[D_STATE], dt;
    load_params(A_log, log_dt, d, ab, dt);

    float s[D_STATE];
    #pragma unroll
    for (int n = 0; n < D_STATE; n++) s[n] = 0.0f;

    const float* up = u + ((size_t)(b * L_SEQ + c * C_LEN)) * D_MODEL + d;
    for (int t = 0; t < C_LEN; t++) {
        float uv = up[(size_t)t * D_MODEL];
        #pragma unroll
        for (int n = 0; n < D_STATE; n++) s[n] = fmaf(ab[n], s[n], uv);
    }
    float* sl = s_local + ((size_t)(b * N_CHUNK + c) * D_STATE) * D_MODEL + d;
    #pragma unroll
    for (int n = 0; n < D_STATE; n++) sl[(size_t)n * D_MODEL] = s[n];
}

// combine: sequential prefix over chunks.
__global__ __launch_bounds__(256) void scan_combine_kernel(const float* __restrict__ s_local,
                                                           const float* __restrict__ A_log,
                                                           const float* __restrict__ log_dt,
                                                           float* __restrict__ s_init) {
    int gid = blockIdx.x * 256 + threadIdx.x;
    int d = gid & (D_MODEL - 1);
    int n = (gid >> 10) & (D_STATE - 1);
    int b = gid >> 14;

    float dt = fminf(1.0f, fmaxf(1e-4f, __expf(log_dt[d])));
    float a = __expf(-__expf(A_log[d * D_STATE + n]) * dt);
    a = fminf(1.0f - 1e-8f, fmaxf(1e-8f, a));
    float aP = a;
    #pragma unroll
    for (int q = 0; q < 6; q++) aP = aP * aP;   // a^64

    float s = 0.0f;
    size_t stride_c = (size_t)D_STATE * D_MODEL;
    const float* sl = s_local + ((size_t)b * N_CHUNK * D_STATE + n) * D_MODEL + d;
    float* si = s_init + ((size_t)b * N_CHUNK * D_STATE + n) * D_MODEL + d;
    si[0] = 0.0f;
    for (int c = 1; c < N_CHUNK; c++) {
        s = fmaf(aP, s, sl[(size_t)(c - 1) * stride_c]);
        si[(size_t)c * stride_c] = s;
    }
}

// pass2: rescan with correct init; fuse y = sum_n cb_n s_n, y *= silu(z); bf16 out.
__global__ __launch_bounds__(256) void scan2_kernel(const float* __restrict__ u,
                                                    const unsigned short* __restrict__ zs,
                                                    const float* __restrict__ A_log,
                                                    const float* __restrict__ Bp,
                                                    const float* __restrict__ Cp,
                                                    const float* __restrict__ log_dt,
                                                    const float* __restrict__ s_init,
                                                    unsigned short* __restrict__ yz) {
    int gid = blockIdx.x * 256 + threadIdx.x;
    int d = gid & (D_MODEL - 1);
    int c = (gid >> 10) & (N_CHUNK - 1);
    int b = gid >> 15;

    float ab[D_STATE], dt;
    load_params(A_log, log_dt, d, ab, dt);
    float cb[D_STATE];
    #pragma unroll
    for (int n = 0; n < D_STATE; n++)
        cb[n] = Cp[d * D_STATE + n] * Bp[d * D_STATE + n] * dt;

    float s[D_STATE];
    const float* si = s_init + ((size_t)(b * N_CHUNK + c) * D_STATE) * D_MODEL + d;
    #pragma unroll
    for (int n = 0; n < D_STATE; n++) s[n] = si[(size_t)n * D_MODEL];

    size_t m0 = (size_t)(b * L_SEQ + c * C_LEN);
    const float* up = u + m0 * D_MODEL + d;
    const unsigned short* zp = zs + m0 * D_MODEL + d;
    unsigned short* yp = yz + m0 * D_MODEL + d;

    for (int t = 0; t < C_LEN; t++) {
        float uv = up[(size_t)t * D_MODEL];
        #pragma unroll
        for (int n = 0; n < D_STATE; n++) s[n] = fmaf(ab[n], s[n], uv);
        float y = 0.0f;
        #pragma unroll
        for (int n = 0; n < D_STATE; n++) y = fmaf(cb[n], s[n], y);
        float zv = bf2f(zp[(size_t)t * D_MODEL]);
        yp[(size_t)t * D_MODEL] = f2bf(y * zv);
    }
}

extern "C" void kernel_launch(void* const* d_in, const int* in_sizes, int n_in,
                              void* d_out, int out_size, void* d_ws, size_t ws_size,
                              hipStream_t stream) {
    const float* x       = (const float*)d_in[0];
    const float* A_log   = (const float*)d_in[1];
    const float* B_param = (const float*)d_in[2];
    const float* C_param = (const float*)d_in[3];
    const float* log_dt  = (const float*)d_in[4];
    const float* in_w    = (const float*)d_in[5];
    const float* in_b    = (const float*)d_in[6];
    const float* out_w   = (const float*)d_in[7];
    const float* out_b   = (const float*)d_in[8];
    const float* ln_g    = (const float*)d_in[9];
    const float* ln_b    = (const float*)d_in[10];
    float* out = (float*)d_out;

    char* ws = (char*)d_ws;
    size_t off = 0;
    unsigned short* xn = (unsigned short*)(ws + off); off += (size_t)M_ROWS * D_MODEL * 2;        // 16 MB
    unsigned short* w1 = (unsigned short*)(ws + off); off += (size_t)2 * D_MODEL * D_MODEL * 2;   // 4 MB
    float*          u  = (float*)(ws + off);          off += (size_t)M_ROWS * D_MODEL * 4;        // 32 MB
    unsigned short* zs = (unsigned short*)(ws + off); off += (size_t)M_ROWS * D_MODEL * 2;        // 16 MB
    unsigned short* yz = (unsigned short*)(ws + off); off += (size_t)M_ROWS * D_MODEL * 2;        // 16 MB
    unsigned short* w2 = (unsigned short*)(ws + off); off += (size_t)D_MODEL * D_MODEL * 2;       // 2 MB
    float* s_local = (float*)(ws + off); off += (size_t)B_SZ * N_CHUNK * D_STATE * D_MODEL * 4;   // 8 MB
    float* s_init  = (float*)(ws + off); off += (size_t)B_SZ * N_CHUNK * D_STATE * D_MODEL * 4;   // 8 MB

    // weights -> bf16
    {
        int n4 = 2 * D_MODEL * D_MODEL / 4;
        conv_bf16_kernel<<<(n4 + 255) / 256, 256, 0, stream>>>(in_w, w1, n4);
    }
    {
        int n4 = D_MODEL * D_MODEL / 4;
        conv_bf16_kernel<<<(n4 + 255) / 256, 256, 0, stream>>>(out_w, w2, n4);
    }

    // layernorm
    ln_kernel<<<M_ROWS, 256, 0, stream>>>(x, ln_g, ln_b, xn);

    // GEMM1: (8192x1024) @ (2048x1024)^T -> u fp32 / silu(z) bf16
    gemm_kernel<1><<<dim3(2 * D_MODEL / 128, M_ROWS / 128), 256, 0, stream>>>(
        xn, w1, in_b, u, zs, nullptr, D_MODEL);

    // chunked SSM scan
    scan1_kernel<<<(B_SZ * N_CHUNK * D_MODEL) / 256, 256, 0, stream>>>(u, A_log, log_dt, s_local);
    scan_combine_kernel<<<(B_SZ * D_STATE * D_MODEL) / 256, 256, 0, stream>>>(s_local, A_log, log_dt, s_init);
    scan2_kernel<<<(B_SZ * N_CHUNK * D_MODEL) / 256, 256, 0, stream>>>(
        u, zs, A_log, B_param, C_param, log_dt, s_init, yz);

    // GEMM2: (8192x1024) @ (1024x1024)^T + resid, clip
    gemm_kernel<2><<<dim3(D_MODEL / 128, M_ROWS / 128), 256, 0, stream>>>(
        yz, w2, out_b, out, nullptr, x, D_MODEL);
}

// Round 4
// 240.511 us; speedup vs baseline: 5.1958x; 1.0136x over previous
//
#include <hip/hip_runtime.h>
#include <hip/hip_bf16.h>

#define D_MODEL 1024
#define D_STATE 16
#define L_SEQ 2048
#define B_SZ 4
#define M_ROWS (B_SZ * L_SEQ)   // 8192
#define N_CHUNK 32               // chunks per sequence
#define C_LEN 64                 // timesteps per chunk (32*64 = 2048)

typedef __attribute__((ext_vector_type(8))) short short8;
typedef __attribute__((ext_vector_type(4))) float f32x4;
typedef unsigned int u32;
#define GLOBAL_AS __attribute__((address_space(1)))
#define LDS_AS __attribute__((address_space(3)))

static __device__ __forceinline__ unsigned short f2bf(float f) {
    unsigned int u = __float_as_uint(f);
    unsigned int r = (u + 0x7FFFu + ((u >> 16) & 1u)) >> 16;   // RNE
    return (unsigned short)r;
}
static __device__ __forceinline__ float bf2f(unsigned short u) {
    return __uint_as_float(((unsigned int)u) << 16);
}

// ---------------- convert fp32 -> bf16 (weights) ----------------
__global__ void conv_bf16_kernel(const float* __restrict__ src,
                                 unsigned short* __restrict__ dst, int n4) {
    int i = blockIdx.x * blockDim.x + threadIdx.x;
    if (i < n4) {
        float4 v = ((const float4*)src)[i];
        ushort4 o;
        o.x = f2bf(v.x); o.y = f2bf(v.y); o.z = f2bf(v.z); o.w = f2bf(v.w);
        ((ushort4*)dst)[i] = o;
    }
}

// ---------------- LayerNorm: x (8192 x 1024) -> xn bf16 ----------------
__global__ __launch_bounds__(256) void ln_kernel(const float* __restrict__ x,
                                                 const float* __restrict__ g,
                                                 const float* __restrict__ b,
                                                 unsigned short* __restrict__ xn) {
    int row = blockIdx.x;
    int t = threadIdx.x;
    const float4* xr = (const float4*)(x + (size_t)row * D_MODEL);
    float4 v = xr[t];
    float s  = v.x + v.y + v.z + v.w;
    float ss = v.x * v.x + v.y * v.y + v.z * v.z + v.w * v.w;
    #pragma unroll
    for (int o = 32; o > 0; o >>= 1) {
        s  += __shfl_down(s,  o);
        ss += __shfl_down(ss, o);
    }
    __shared__ float sbuf[8];
    int wid = t >> 6;
    if ((t & 63) == 0) { sbuf[wid] = s; sbuf[4 + wid] = ss; }
    __syncthreads();
    float S  = sbuf[0] + sbuf[1] + sbuf[2] + sbuf[3];
    float SS = sbuf[4] + sbuf[5] + sbuf[6] + sbuf[7];
    float mu  = S * (1.0f / D_MODEL);
    float var = SS * (1.0f / D_MODEL) - mu * mu;
    float inv = rsqrtf(var + 1e-5f);
    float4 gv = ((const float4*)g)[t];
    float4 bv = ((const float4*)b)[t];
    ushort4 o;
    o.x = f2bf((v.x - mu) * inv * gv.x + bv.x);
    o.y = f2bf((v.y - mu) * inv * gv.y + bv.y);
    o.z = f2bf((v.z - mu) * inv * gv.z + bv.z);
    o.w = f2bf((v.w - mu) * inv * gv.w + bv.w);
    ((ushort4*)(xn + (size_t)row * D_MODEL))[t] = o;
}

// ---------------- GEMM (NT, bf16 MFMA, LDS-staged, XOR-swizzled) ----------------
// D[m][n] = sum_k A[m][k] * Bt[n][k] + bias[n]
// Block: 256 threads (4 waves, 2x2), tile 128x128, BK=32.
// LDS layout: two 64-row halves of 4KB each. Within a half, 16B slot index
// for (row r6, k-chunk q) is  r6*4 + (q ^ ((r6>>1)&3))  — XOR swizzle so the
// 16 lanes of each quad-group hit all 8 bank-quads exactly twice (2-way free).
// Staging writes are forced to slot=t (global_load_lds lane-contiguous), so the
// swizzle is applied on the global SOURCE k-chunk instead.
template<int MODE>
__global__ __launch_bounds__(256) void gemm_kernel(const unsigned short* __restrict__ A,
                                                   const unsigned short* __restrict__ Bt,
                                                   const float* __restrict__ bias,
                                                   float* __restrict__ out_f,
                                                   unsigned short* __restrict__ out_bf,
                                                   const float* __restrict__ resid,
                                                   int K) {
    __shared__ unsigned short lA[128 * 32];   // 8 KB
    __shared__ unsigned short lB[128 * 32];   // 8 KB

    int t = threadIdx.x;
    int lane = t & 63;
    int wave = t >> 6;
    int wm = wave >> 1, wn = wave & 1;
    int m0 = blockIdx.y * 128;
    int n0 = blockIdx.x * 128;
    int row = lane & 15;
    int quad = lane >> 4;

    // staging: thread t owns LDS slot t (16B). It must therefore fetch the
    // swizzled k-chunk: stored chunk (t&3) corresponds to global chunk
    // (t&3) ^ f(row), f(row) = (row>>1)&3 = (t>>3)&3.
    int sr = t >> 2;
    int sc = ((t & 3) ^ ((t >> 3) & 3)) * 8;
    const unsigned short* gA0 = A + (size_t)(m0 + sr) * K + sc;
    const unsigned short* gA1 = A + (size_t)(m0 + 64 + sr) * K + sc;
    const unsigned short* gB0 = Bt + (size_t)(n0 + sr) * K + sc;
    const unsigned short* gB1 = Bt + (size_t)(n0 + 64 + sr) * K + sc;

    // fragment read offsets (element index into lA/lB), swizzled
    int offA[4], offB[4];
    #pragma unroll
    for (int i = 0; i < 4; i++) {
        int r6 = i * 16 + row;                       // within-half row
        int slotA = r6 * 4 + (quad ^ ((r6 >> 1) & 3));
        offA[i] = wm * 2048 + slotA * 8;
        offB[i] = wn * 2048 + slotA * 8;             // same formula for B
    }

    f32x4 acc[4][4] = {};

    for (int kk = 0; kk < K; kk += 32) {
        __builtin_amdgcn_global_load_lds((const GLOBAL_AS u32*)(gA0 + kk),
                                         (LDS_AS u32*)&lA[t * 8], 16, 0, 0);
        __builtin_amdgcn_global_load_lds((const GLOBAL_AS u32*)(gA1 + kk),
                                         (LDS_AS u32*)&lA[2048 + t * 8], 16, 0, 0);
        __builtin_amdgcn_global_load_lds((const GLOBAL_AS u32*)(gB0 + kk),
                                         (LDS_AS u32*)&lB[t * 8], 16, 0, 0);
        __builtin_amdgcn_global_load_lds((const GLOBAL_AS u32*)(gB1 + kk),
                                         (LDS_AS u32*)&lB[2048 + t * 8], 16, 0, 0);
        __syncthreads();

        short8 a[4], b[4];
        #pragma unroll
        for (int i = 0; i < 4; i++) a[i] = *(const short8*)&lA[offA[i]];
        #pragma unroll
        for (int j = 0; j < 4; j++) b[j] = *(const short8*)&lB[offB[j]];
        #pragma unroll
        for (int i = 0; i < 4; i++)
            #pragma unroll
            for (int j = 0; j < 4; j++)
                acc[i][j] = __builtin_amdgcn_mfma_f32_16x16x32_bf16(a[i], b[j], acc[i][j], 0, 0, 0);
        __syncthreads();
    }

    // epilogue: C/D layout col = lane&15, row = quad*4 + reg
    int col = row;
    #pragma unroll
    for (int i = 0; i < 4; i++) {
        #pragma unroll
        for (int j = 0; j < 4; j++) {
            int n = n0 + wn * 64 + j * 16 + col;
            float bs = bias[n];
            #pragma unroll
            for (int r = 0; r < 4; r++) {
                int m = m0 + wm * 64 + i * 16 + quad * 4 + r;
                float v = acc[i][j][r] + bs;
                if (MODE == 1) {
                    if (n < D_MODEL) {
                        out_f[(size_t)m * D_MODEL + n] = v;
                    } else {
                        float sv = v / (1.0f + __expf(-v));
                        out_bf[(size_t)m * D_MODEL + (n - D_MODEL)] = f2bf(sv);
                    }
                } else {
                    float y = v + resid[(size_t)m * D_MODEL + n];
                    y = fminf(10.0f, fmaxf(-10.0f, y));
                    out_f[(size_t)m * D_MODEL + n] = y;
                }
            }
        }
    }
}

// ---------------- chunked SSM scan ----------------
static __device__ __forceinline__ void load_params(const float* __restrict__ A_log,
                                                   const float* __restrict__ log_dt,
                                                   int d, float* ab, float& dt_out) {
    float dt = fminf(1.0f, fmaxf(1e-4f, __expf(log_dt[d])));
    #pragma unroll
    for (int n = 0; n < D_STATE; n++) {
        float a = __expf(-__expf(A_log[d * D_STATE + n]) * dt);
        ab[n] = fminf(1.0f - 1e-8f, fmaxf(1e-8f, a));
    }
    dt_out = dt;
}

// pass1: zero-init local scan of each chunk; writes chunk-final states.
__global__ __launch_bounds__(256) void scan1_kernel(const float* __restrict__ u,
                                                    const float* __restrict__ A_log,
                                                    const float* __restrict__ log_dt,
                                                    float* __restrict__ s_local) {
    int gid = blockIdx.x * 256 + threadIdx.x;
    int d = gid & (D_MODEL - 1);
    int c = (gid >> 10) & (N_CHUNK - 1);
    int b = gid >> 15;

    float ab[D_STATE], dt;
    load_params(A_log, log_dt, d, ab, dt);

    float s[D_STATE];
    #pragma unroll
    for (int n = 0; n < D_STATE; n++) s[n] = 0.0f;

    const float* up = u + ((size_t)(b * L_SEQ + c * C_LEN)) * D_MODEL + d;
    for (int t = 0; t < C_LEN; t++) {
        float uv = up[(size_t)t * D_MODEL];
        #pragma unroll
        for (int n = 0; n < D_STATE; n++) s[n] = fmaf(ab[n], s[n], uv);
    }
    float* sl = s_local + ((size_t)(b * N_CHUNK + c) * D_STATE) * D_MODEL + d;
    #pragma unroll
    for (int n = 0; n < D_STATE; n++) sl[(size_t)n * D_MODEL] = s[n];
}

// combine: sequential prefix over chunks.
__global__ __launch_bounds__(256) void scan_combine_kernel(const float* __restrict__ s_local,
                                                           const float* __restrict__ A_log,
                                                           const float* __restrict__ log_dt,
                                                           float* __restrict__ s_init) {
    int gid = blockIdx.x * 256 + threadIdx.x;
    int d = gid & (D_MODEL - 1);
    int n = (gid >> 10) & (D_STATE - 1);
    int b = gid >> 14;

    float dt = fminf(1.0f, fmaxf(1e-4f, __expf(log_dt[d])));
    float a = __expf(-__expf(A_log[d * D_STATE + n]) * dt);
    a = fminf(1.0f - 1e-8f, fmaxf(1e-8f, a));
    float aP = a;
    #pragma unroll
    for (int q = 0; q < 6; q++) aP = aP * aP;   // a^64

    float s = 0.0f;
    size_t stride_c = (size_t)D_STATE * D_MODEL;
    const float* sl = s_local + ((size_t)b * N_CHUNK * D_STATE + n) * D_MODEL + d;
    float* si = s_init + ((size_t)b * N_CHUNK * D_STATE + n) * D_MODEL + d;
    si[0] = 0.0f;
    for (int c = 1; c < N_CHUNK; c++) {
        s = fmaf(aP, s, sl[(size_t)(c - 1) * stride_c]);
        si[(size_t)c * stride_c] = s;
    }
}

// pass2: rescan with correct init; fuse y = sum_n cb_n s_n, y *= silu(z); bf16 out.
__global__ __launch_bounds__(256) void scan2_kernel(const float* __restrict__ u,
                                                    const unsigned short* __restrict__ zs,
                                                    const float* __restrict__ A_log,
                                                    const float* __restrict__ Bp,
                                                    const float* __restrict__ Cp,
                                                    const float* __restrict__ log_dt,
                                                    const float* __restrict__ s_init,
                                                    unsigned short* __restrict__ yz) {
    int gid = blockIdx.x * 256 + threadIdx.x;
    int d = gid & (D_MODEL - 1);
    int c = (gid >> 10) & (N_CHUNK - 1);
    int b = gid >> 15;

    float ab[D_STATE], dt;
    load_params(A_log, log_dt, d, ab, dt);
    float cb[D_STATE];
    #pragma unroll
    for (int n = 0; n < D_STATE; n++)
        cb[n] = Cp[d * D_STATE + n] * Bp[d * D_STATE + n] * dt;

    float s[D_STATE];
    const float* si = s_init + ((size_t)(b * N_CHUNK + c) * D_STATE) * D_MODEL + d;
    #pragma unroll
    for (int n = 0; n < D_STATE; n++) s[n] = si[(size_t)n * D_MODEL];

    size_t m0 = (size_t)(b * L_SEQ + c * C_LEN);
    const float* up = u + m0 * D_MODEL + d;
    const unsigned short* zp = zs + m0 * D_MODEL + d;
    unsigned short* yp = yz + m0 * D_MODEL + d;

    for (int t = 0; t < C_LEN; t++) {
        float uv = up[(size_t)t * D_MODEL];
        #pragma unroll
        for (int n = 0; n < D_STATE; n++) s[n] = fmaf(ab[n], s[n], uv);
        float y = 0.0f;
        #pragma unroll
        for (int n = 0; n < D_STATE; n++) y = fmaf(cb[n], s[n], y);
        float zv = bf2f(zp[(size_t)t * D_MODEL]);
        yp[(size_t)t * D_MODEL] = f2bf(y * zv);
    }
}

extern "C" void kernel_launch(void* const* d_in, const int* in_sizes, int n_in,
                              void* d_out, int out_size, void* d_ws, size_t ws_size,
                              hipStream_t stream) {
    const float* x       = (const float*)d_in[0];
    const float* A_log   = (const float*)d_in[1];
    const float* B_param = (const float*)d_in[2];
    const float* C_param = (const float*)d_in[3];
    const float* log_dt  = (const float*)d_in[4];
    const float* in_w    = (const float*)d_in[5];
    const float* in_b    = (const float*)d_in[6];
    const float* out_w   = (const float*)d_in[7];
    const float* out_b   = (const float*)d_in[8];
    const float* ln_g    = (const float*)d_in[9];
    const float* ln_b    = (const float*)d_in[10];
    float* out = (float*)d_out;

    char* ws = (char*)d_ws;
    size_t off = 0;
    unsigned short* xn = (unsigned short*)(ws + off); off += (size_t)M_ROWS * D_MODEL * 2;        // 16 MB
    unsigned short* w1 = (unsigned short*)(ws + off); off += (size_t)2 * D_MODEL * D_MODEL * 2;   // 4 MB
    float*          u  = (float*)(ws + off);          off += (size_t)M_ROWS * D_MODEL * 4;        // 32 MB
    unsigned short* zs = (unsigned short*)(ws + off); off += (size_t)M_ROWS * D_MODEL * 2;        // 16 MB
    unsigned short* yz = (unsigned short*)(ws + off); off += (size_t)M_ROWS * D_MODEL * 2;        // 16 MB
    unsigned short* w2 = (unsigned short*)(ws + off); off += (size_t)D_MODEL * D_MODEL * 2;       // 2 MB
    float* s_local = (float*)(ws + off); off += (size_t)B_SZ * N_CHUNK * D_STATE * D_MODEL * 4;   // 8 MB
    float* s_init  = (float*)(ws + off); off += (size_t)B_SZ * N_CHUNK * D_STATE * D_MODEL * 4;   // 8 MB

    // weights -> bf16
    {
        int n4 = 2 * D_MODEL * D_MODEL / 4;
        conv_bf16_kernel<<<(n4 + 255) / 256, 256, 0, stream>>>(in_w, w1, n4);
    }
    {
        int n4 = D_MODEL * D_MODEL / 4;
        conv_bf16_kernel<<<(n4 + 255) / 256, 256, 0, stream>>>(out_w, w2, n4);
    }

    // layernorm
    ln_kernel<<<M_ROWS, 256, 0, stream>>>(x, ln_g, ln_b, xn);

    // GEMM1: (8192x1024) @ (2048x1024)^T -> u fp32 / silu(z) bf16
    gemm_kernel<1><<<dim3(2 * D_MODEL / 128, M_ROWS / 128), 256, 0, stream>>>(
        xn, w1, in_b, u, zs, nullptr, D_MODEL);

    // chunked SSM scan
    scan1_kernel<<<(B_SZ * N_CHUNK * D_MODEL) / 256, 256, 0, stream>>>(u, A_log, log_dt, s_local);
    scan_combine_kernel<<<(B_SZ * D_STATE * D_MODEL) / 256, 256, 0, stream>>>(s_local, A_log, log_dt, s_init);
    scan2_kernel<<<(B_SZ * N_CHUNK * D_MODEL) / 256, 256, 0, stream>>>(
        u, zs, A_log, B_param, C_param, log_dt, s_init, yz);

    // GEMM2: (8192x1024) @ (1024x1024)^T + resid, clip
    gemm_kernel<2><<<dim3(D_MODEL / 128, M_ROWS / 128), 256, 0, stream>>>(
        yz, w2, out_b, out, nullptr, x, D_MODEL);
}

// Round 5
// 222.991 us; speedup vs baseline: 5.6040x; 1.0786x over previous
//
#include <hip/hip_runtime.h>
#include <hip/hip_bf16.h>

#define D_MODEL 1024
#define D_STATE 16
#define L_SEQ 2048
#define B_SZ 4
#define M_ROWS (B_SZ * L_SEQ)   // 8192
#define N_CHUNK 32               // chunks per sequence
#define C_LEN 64                 // timesteps per chunk (32*64 = 2048)

typedef __attribute__((ext_vector_type(8))) short short8;
typedef __attribute__((ext_vector_type(4))) float f32x4;
typedef unsigned int u32;
#define GLOBAL_AS __attribute__((address_space(1)))
#define LDS_AS __attribute__((address_space(3)))

static __device__ __forceinline__ unsigned short f2bf(float f) {
    unsigned int u = __float_as_uint(f);
    unsigned int r = (u + 0x7FFFu + ((u >> 16) & 1u)) >> 16;   // RNE
    return (unsigned short)r;
}
static __device__ __forceinline__ float bf2f(unsigned short u) {
    return __uint_as_float(((unsigned int)u) << 16);
}

// ---------------- convert fp32 -> bf16 (weights) ----------------
__global__ void conv_bf16_kernel(const float* __restrict__ src,
                                 unsigned short* __restrict__ dst, int n4) {
    int i = blockIdx.x * blockDim.x + threadIdx.x;
    if (i < n4) {
        float4 v = ((const float4*)src)[i];
        ushort4 o;
        o.x = f2bf(v.x); o.y = f2bf(v.y); o.z = f2bf(v.z); o.w = f2bf(v.w);
        ((ushort4*)dst)[i] = o;
    }
}

// ---------------- LayerNorm: x (8192 x 1024) -> xn bf16 ----------------
__global__ __launch_bounds__(256) void ln_kernel(const float* __restrict__ x,
                                                 const float* __restrict__ g,
                                                 const float* __restrict__ b,
                                                 unsigned short* __restrict__ xn) {
    int row = blockIdx.x;
    int t = threadIdx.x;
    const float4* xr = (const float4*)(x + (size_t)row * D_MODEL);
    float4 v = xr[t];
    float s  = v.x + v.y + v.z + v.w;
    float ss = v.x * v.x + v.y * v.y + v.z * v.z + v.w * v.w;
    #pragma unroll
    for (int o = 32; o > 0; o >>= 1) {
        s  += __shfl_down(s,  o);
        ss += __shfl_down(ss, o);
    }
    __shared__ float sbuf[8];
    int wid = t >> 6;
    if ((t & 63) == 0) { sbuf[wid] = s; sbuf[4 + wid] = ss; }
    __syncthreads();
    float S  = sbuf[0] + sbuf[1] + sbuf[2] + sbuf[3];
    float SS = sbuf[4] + sbuf[5] + sbuf[6] + sbuf[7];
    float mu  = S * (1.0f / D_MODEL);
    float var = SS * (1.0f / D_MODEL) - mu * mu;
    float inv = rsqrtf(var + 1e-5f);
    float4 gv = ((const float4*)g)[t];
    float4 bv = ((const float4*)b)[t];
    ushort4 o;
    o.x = f2bf((v.x - mu) * inv * gv.x + bv.x);
    o.y = f2bf((v.y - mu) * inv * gv.y + bv.y);
    o.z = f2bf((v.z - mu) * inv * gv.z + bv.z);
    o.w = f2bf((v.w - mu) * inv * gv.w + bv.w);
    ((ushort4*)(xn + (size_t)row * D_MODEL))[t] = o;
}

// ---------------- GEMM1: 128x256 block, 4 waves of 64x128 ----------------
// D[m][n] = sum_k A[m][k]*Bt[n][k] + bias[n];  n<1024 -> u bf16; else silu -> zs
__global__ __launch_bounds__(256, 2) void gemm1_kernel(const unsigned short* __restrict__ A,
                                                       const unsigned short* __restrict__ Bt,
                                                       const float* __restrict__ bias,
                                                       unsigned short* __restrict__ u_bf,
                                                       unsigned short* __restrict__ zs) {
    __shared__ unsigned short lA[128 * 32];   // 8 KB
    __shared__ unsigned short lB[256 * 32];   // 16 KB
    const int K = D_MODEL;

    int t = threadIdx.x;
    int lane = t & 63;
    int wave = t >> 6;
    int wm = wave >> 1, wn = wave & 1;
    int m0 = blockIdx.y * 128;
    int n0 = blockIdx.x * 256;
    int row = lane & 15;
    int quad = lane >> 4;

    // staging: thread t owns 16B slot t in each 64-row half; fetch swizzled k-chunk
    int sr = t >> 2;
    int sc = ((t & 3) ^ ((t >> 3) & 3)) * 8;
    const unsigned short* gA0 = A + (size_t)(m0 + sr) * K + sc;
    const unsigned short* gA1 = A + (size_t)(m0 + 64 + sr) * K + sc;
    const unsigned short* gB0 = Bt + (size_t)(n0 + sr) * K + sc;
    const unsigned short* gB1 = Bt + (size_t)(n0 + 64 + sr) * K + sc;
    const unsigned short* gB2 = Bt + (size_t)(n0 + 128 + sr) * K + sc;
    const unsigned short* gB3 = Bt + (size_t)(n0 + 192 + sr) * K + sc;

    // fragment read offsets (swizzled)
    int offA[4], offB[8];
    #pragma unroll
    for (int i = 0; i < 4; i++) {
        int r6 = i * 16 + row;
        int slot = r6 * 4 + (quad ^ ((r6 >> 1) & 3));
        offA[i] = wm * 2048 + slot * 8;
    }
    #pragma unroll
    for (int j = 0; j < 8; j++) {
        int r8 = wn * 128 + j * 16 + row;
        int half = r8 >> 6, r6 = r8 & 63;
        int slot = r6 * 4 + (quad ^ ((r6 >> 1) & 3));
        offB[j] = half * 2048 + slot * 8;
    }

    f32x4 acc[4][8] = {};

    for (int kk = 0; kk < K; kk += 32) {
        __builtin_amdgcn_global_load_lds((const GLOBAL_AS u32*)(gA0 + kk),
                                         (LDS_AS u32*)&lA[t * 8], 16, 0, 0);
        __builtin_amdgcn_global_load_lds((const GLOBAL_AS u32*)(gA1 + kk),
                                         (LDS_AS u32*)&lA[2048 + t * 8], 16, 0, 0);
        __builtin_amdgcn_global_load_lds((const GLOBAL_AS u32*)(gB0 + kk),
                                         (LDS_AS u32*)&lB[t * 8], 16, 0, 0);
        __builtin_amdgcn_global_load_lds((const GLOBAL_AS u32*)(gB1 + kk),
                                         (LDS_AS u32*)&lB[2048 + t * 8], 16, 0, 0);
        __builtin_amdgcn_global_load_lds((const GLOBAL_AS u32*)(gB2 + kk),
                                         (LDS_AS u32*)&lB[4096 + t * 8], 16, 0, 0);
        __builtin_amdgcn_global_load_lds((const GLOBAL_AS u32*)(gB3 + kk),
                                         (LDS_AS u32*)&lB[6144 + t * 8], 16, 0, 0);
        __syncthreads();

        short8 a[4];
        #pragma unroll
        for (int i = 0; i < 4; i++) a[i] = *(const short8*)&lA[offA[i]];
        #pragma unroll
        for (int j = 0; j < 8; j++) {
            short8 b = *(const short8*)&lB[offB[j]];
            #pragma unroll
            for (int i = 0; i < 4; i++)
                acc[i][j] = __builtin_amdgcn_mfma_f32_16x16x32_bf16(a[i], b, acc[i][j], 0, 0, 0);
        }
        __syncthreads();
    }

    // epilogue: C/D layout col = lane&15, row = quad*4 + reg
    int col = row;
    #pragma unroll
    for (int j = 0; j < 8; j++) {
        int n = n0 + wn * 128 + j * 16 + col;
        float bs = bias[n];
        #pragma unroll
        for (int i = 0; i < 4; i++) {
            #pragma unroll
            for (int r = 0; r < 4; r++) {
                int m = m0 + wm * 64 + i * 16 + quad * 4 + r;
                float v = acc[i][j][r] + bs;
                if (n < D_MODEL) {
                    u_bf[(size_t)m * D_MODEL + n] = f2bf(v);
                } else {
                    float sv = v / (1.0f + __expf(-v));
                    zs[(size_t)m * D_MODEL + (n - D_MODEL)] = f2bf(sv);
                }
            }
        }
    }
}

// ---------------- GEMM2: 128x128 block, 4 waves of 64x64 (resid+clip) ----------------
__global__ __launch_bounds__(256) void gemm2_kernel(const unsigned short* __restrict__ A,
                                                    const unsigned short* __restrict__ Bt,
                                                    const float* __restrict__ bias,
                                                    float* __restrict__ out_f,
                                                    const float* __restrict__ resid) {
    __shared__ unsigned short lA[128 * 32];   // 8 KB
    __shared__ unsigned short lB[128 * 32];   // 8 KB
    const int K = D_MODEL;

    int t = threadIdx.x;
    int lane = t & 63;
    int wave = t >> 6;
    int wm = wave >> 1, wn = wave & 1;
    int m0 = blockIdx.y * 128;
    int n0 = blockIdx.x * 128;
    int row = lane & 15;
    int quad = lane >> 4;

    int sr = t >> 2;
    int sc = ((t & 3) ^ ((t >> 3) & 3)) * 8;
    const unsigned short* gA0 = A + (size_t)(m0 + sr) * K + sc;
    const unsigned short* gA1 = A + (size_t)(m0 + 64 + sr) * K + sc;
    const unsigned short* gB0 = Bt + (size_t)(n0 + sr) * K + sc;
    const unsigned short* gB1 = Bt + (size_t)(n0 + 64 + sr) * K + sc;

    int offA[4], offB[4];
    #pragma unroll
    for (int i = 0; i < 4; i++) {
        int r6 = i * 16 + row;
        int slot = r6 * 4 + (quad ^ ((r6 >> 1) & 3));
        offA[i] = wm * 2048 + slot * 8;
        offB[i] = wn * 2048 + slot * 8;
    }

    f32x4 acc[4][4] = {};

    for (int kk = 0; kk < K; kk += 32) {
        __builtin_amdgcn_global_load_lds((const GLOBAL_AS u32*)(gA0 + kk),
                                         (LDS_AS u32*)&lA[t * 8], 16, 0, 0);
        __builtin_amdgcn_global_load_lds((const GLOBAL_AS u32*)(gA1 + kk),
                                         (LDS_AS u32*)&lA[2048 + t * 8], 16, 0, 0);
        __builtin_amdgcn_global_load_lds((const GLOBAL_AS u32*)(gB0 + kk),
                                         (LDS_AS u32*)&lB[t * 8], 16, 0, 0);
        __builtin_amdgcn_global_load_lds((const GLOBAL_AS u32*)(gB1 + kk),
                                         (LDS_AS u32*)&lB[2048 + t * 8], 16, 0, 0);
        __syncthreads();

        short8 a[4], b[4];
        #pragma unroll
        for (int i = 0; i < 4; i++) a[i] = *(const short8*)&lA[offA[i]];
        #pragma unroll
        for (int j = 0; j < 4; j++) b[j] = *(const short8*)&lB[offB[j]];
        #pragma unroll
        for (int i = 0; i < 4; i++)
            #pragma unroll
            for (int j = 0; j < 4; j++)
                acc[i][j] = __builtin_amdgcn_mfma_f32_16x16x32_bf16(a[i], b[j], acc[i][j], 0, 0, 0);
        __syncthreads();
    }

    int col = row;
    #pragma unroll
    for (int i = 0; i < 4; i++) {
        #pragma unroll
        for (int j = 0; j < 4; j++) {
            int n = n0 + wn * 64 + j * 16 + col;
            float bs = bias[n];
            #pragma unroll
            for (int r = 0; r < 4; r++) {
                int m = m0 + wm * 64 + i * 16 + quad * 4 + r;
                float y = acc[i][j][r] + bs + resid[(size_t)m * D_MODEL + n];
                y = fminf(10.0f, fmaxf(-10.0f, y));
                out_f[(size_t)m * D_MODEL + n] = y;
            }
        }
    }
}

// ---------------- chunked SSM scan (u is bf16 now) ----------------
static __device__ __forceinline__ void load_params(const float* __restrict__ A_log,
                                                   const float* __restrict__ log_dt,
                                                   int d, float* ab, float& dt_out) {
    float dt = fminf(1.0f, fmaxf(1e-4f, __expf(log_dt[d])));
    #pragma unroll
    for (int n = 0; n < D_STATE; n++) {
        float a = __expf(-__expf(A_log[d * D_STATE + n]) * dt);
        ab[n] = fminf(1.0f - 1e-8f, fmaxf(1e-8f, a));
    }
    dt_out = dt;
}

// pass1: zero-init local scan of each chunk; writes chunk-final states.
__global__ __launch_bounds__(256) void scan1_kernel(const unsigned short* __restrict__ u,
                                                    const float* __restrict__ A_log,
                                                    const float* __restrict__ log_dt,
                                                    float* __restrict__ s_local) {
    int gid = blockIdx.x * 256 + threadIdx.x;
    int d = gid & (D_MODEL - 1);
    int c = (gid >> 10) & (N_CHUNK - 1);
    int b = gid >> 15;

    float ab[D_STATE], dt;
    load_params(A_log, log_dt, d, ab, dt);

    float s[D_STATE];
    #pragma unroll
    for (int n = 0; n < D_STATE; n++) s[n] = 0.0f;

    const unsigned short* up = u + ((size_t)(b * L_SEQ + c * C_LEN)) * D_MODEL + d;
    for (int t = 0; t < C_LEN; t++) {
        float uv = bf2f(up[(size_t)t * D_MODEL]);
        #pragma unroll
        for (int n = 0; n < D_STATE; n++) s[n] = fmaf(ab[n], s[n], uv);
    }
    float* sl = s_local + ((size_t)(b * N_CHUNK + c) * D_STATE) * D_MODEL + d;
    #pragma unroll
    for (int n = 0; n < D_STATE; n++) sl[(size_t)n * D_MODEL] = s[n];
}

// combine: sequential prefix over chunks.
__global__ __launch_bounds__(256) void scan_combine_kernel(const float* __restrict__ s_local,
                                                           const float* __restrict__ A_log,
                                                           const float* __restrict__ log_dt,
                                                           float* __restrict__ s_init) {
    int gid = blockIdx.x * 256 + threadIdx.x;
    int d = gid & (D_MODEL - 1);
    int n = (gid >> 10) & (D_STATE - 1);
    int b = gid >> 14;

    float dt = fminf(1.0f, fmaxf(1e-4f, __expf(log_dt[d])));
    float a = __expf(-__expf(A_log[d * D_STATE + n]) * dt);
    a = fminf(1.0f - 1e-8f, fmaxf(1e-8f, a));
    float aP = a;
    #pragma unroll
    for (int q = 0; q < 6; q++) aP = aP * aP;   // a^64

    float s = 0.0f;
    size_t stride_c = (size_t)D_STATE * D_MODEL;
    const float* sl = s_local + ((size_t)b * N_CHUNK * D_STATE + n) * D_MODEL + d;
    float* si = s_init + ((size_t)b * N_CHUNK * D_STATE + n) * D_MODEL + d;
    si[0] = 0.0f;
    for (int c = 1; c < N_CHUNK; c++) {
        s = fmaf(aP, s, sl[(size_t)(c - 1) * stride_c]);
        si[(size_t)c * stride_c] = s;
    }
}

// pass2: rescan with correct init; fuse y = sum_n cb_n s_n, y *= silu(z); bf16 out.
__global__ __launch_bounds__(256) void scan2_kernel(const unsigned short* __restrict__ u,
                                                    const unsigned short* __restrict__ zs,
                                                    const float* __restrict__ A_log,
                                                    const float* __restrict__ Bp,
                                                    const float* __restrict__ Cp,
                                                    const float* __restrict__ log_dt,
                                                    const float* __restrict__ s_init,
                                                    unsigned short* __restrict__ yz) {
    int gid = blockIdx.x * 256 + threadIdx.x;
    int d = gid & (D_MODEL - 1);
    int c = (gid >> 10) & (N_CHUNK - 1);
    int b = gid >> 15;

    float ab[D_STATE], dt;
    load_params(A_log, log_dt, d, ab, dt);
    float cb[D_STATE];
    #pragma unroll
    for (int n = 0; n < D_STATE; n++)
        cb[n] = Cp[d * D_STATE + n] * Bp[d * D_STATE + n] * dt;

    float s[D_STATE];
    const float* si = s_init + ((size_t)(b * N_CHUNK + c) * D_STATE) * D_MODEL + d;
    #pragma unroll
    for (int n = 0; n < D_STATE; n++) s[n] = si[(size_t)n * D_MODEL];

    size_t m0 = (size_t)(b * L_SEQ + c * C_LEN);
    const unsigned short* up = u + m0 * D_MODEL + d;
    const unsigned short* zp = zs + m0 * D_MODEL + d;
    unsigned short* yp = yz + m0 * D_MODEL + d;

    for (int t = 0; t < C_LEN; t++) {
        float uv = bf2f(up[(size_t)t * D_MODEL]);
        #pragma unroll
        for (int n = 0; n < D_STATE; n++) s[n] = fmaf(ab[n], s[n], uv);
        float y = 0.0f;
        #pragma unroll
        for (int n = 0; n < D_STATE; n++) y = fmaf(cb[n], s[n], y);
        float zv = bf2f(zp[(size_t)t * D_MODEL]);
        yp[(size_t)t * D_MODEL] = f2bf(y * zv);
    }
}

extern "C" void kernel_launch(void* const* d_in, const int* in_sizes, int n_in,
                              void* d_out, int out_size, void* d_ws, size_t ws_size,
                              hipStream_t stream) {
    const float* x       = (const float*)d_in[0];
    const float* A_log   = (const float*)d_in[1];
    const float* B_param = (const float*)d_in[2];
    const float* C_param = (const float*)d_in[3];
    const float* log_dt  = (const float*)d_in[4];
    const float* in_w    = (const float*)d_in[5];
    const float* in_b    = (const float*)d_in[6];
    const float* out_w   = (const float*)d_in[7];
    const float* out_b   = (const float*)d_in[8];
    const float* ln_g    = (const float*)d_in[9];
    const float* ln_b    = (const float*)d_in[10];
    float* out = (float*)d_out;

    char* ws = (char*)d_ws;
    size_t off = 0;
    unsigned short* xn = (unsigned short*)(ws + off); off += (size_t)M_ROWS * D_MODEL * 2;        // 16 MB
    unsigned short* w1 = (unsigned short*)(ws + off); off += (size_t)2 * D_MODEL * D_MODEL * 2;   // 4 MB
    unsigned short* u  = (unsigned short*)(ws + off); off += (size_t)M_ROWS * D_MODEL * 2;        // 16 MB
    unsigned short* zs = (unsigned short*)(ws + off); off += (size_t)M_ROWS * D_MODEL * 2;        // 16 MB
    unsigned short* yz = (unsigned short*)(ws + off); off += (size_t)M_ROWS * D_MODEL * 2;        // 16 MB
    unsigned short* w2 = (unsigned short*)(ws + off); off += (size_t)D_MODEL * D_MODEL * 2;       // 2 MB
    float* s_local = (float*)(ws + off); off += (size_t)B_SZ * N_CHUNK * D_STATE * D_MODEL * 4;   // 8 MB
    float* s_init  = (float*)(ws + off); off += (size_t)B_SZ * N_CHUNK * D_STATE * D_MODEL * 4;   // 8 MB

    // weights -> bf16
    {
        int n4 = 2 * D_MODEL * D_MODEL / 4;
        conv_bf16_kernel<<<(n4 + 255) / 256, 256, 0, stream>>>(in_w, w1, n4);
    }
    {
        int n4 = D_MODEL * D_MODEL / 4;
        conv_bf16_kernel<<<(n4 + 255) / 256, 256, 0, stream>>>(out_w, w2, n4);
    }

    // layernorm
    ln_kernel<<<M_ROWS, 256, 0, stream>>>(x, ln_g, ln_b, xn);

    // GEMM1: (8192x1024) @ (2048x1024)^T -> u bf16 / silu(z) bf16
    gemm1_kernel<<<dim3(2 * D_MODEL / 256, M_ROWS / 128), 256, 0, stream>>>(
        xn, w1, in_b, u, zs);

    // chunked SSM scan
    scan1_kernel<<<(B_SZ * N_CHUNK * D_MODEL) / 256, 256, 0, stream>>>(u, A_log, log_dt, s_local);
    scan_combine_kernel<<<(B_SZ * D_STATE * D_MODEL) / 256, 256, 0, stream>>>(s_local, A_log, log_dt, s_init);
    scan2_kernel<<<(B_SZ * N_CHUNK * D_MODEL) / 256, 256, 0, stream>>>(
        u, zs, A_log, B_param, C_param, log_dt, s_init, yz);

    // GEMM2: (8192x1024) @ (1024x1024)^T + resid, clip
    gemm2_kernel<<<dim3(D_MODEL / 128, M_ROWS / 128), 256, 0, stream>>>(
        yz, w2, out_b, out, x);
}

// Round 6
// 222.135 us; speedup vs baseline: 5.6256x; 1.0039x over previous
//
#include <hip/hip_runtime.h>
#include <hip/hip_bf16.h>

#define D_MODEL 1024
#define D_STATE 16
#define L_SEQ 2048
#define B_SZ 4
#define M_ROWS (B_SZ * L_SEQ)   // 8192
#define N_CHUNK 32               // chunks per sequence
#define C_LEN 64                 // timesteps per chunk (32*64 = 2048)

typedef __attribute__((ext_vector_type(8))) short short8;
typedef __attribute__((ext_vector_type(4))) float f32x4;
typedef unsigned int u32;
typedef __attribute__((ext_vector_type(4))) u32 u32x4;

static __device__ __forceinline__ unsigned short f2bf(float f) {
    unsigned int u = __float_as_uint(f);
    unsigned int r = (u + 0x7FFFu + ((u >> 16) & 1u)) >> 16;   // RNE
    return (unsigned short)r;
}
static __device__ __forceinline__ float bf2f(unsigned short u) {
    return __uint_as_float(((unsigned int)u) << 16);
}

// ---------------- convert fp32 -> bf16 (weights) ----------------
__global__ void conv_bf16_kernel(const float* __restrict__ src,
                                 unsigned short* __restrict__ dst, int n4) {
    int i = blockIdx.x * blockDim.x + threadIdx.x;
    if (i < n4) {
        float4 v = ((const float4*)src)[i];
        ushort4 o;
        o.x = f2bf(v.x); o.y = f2bf(v.y); o.z = f2bf(v.z); o.w = f2bf(v.w);
        ((ushort4*)dst)[i] = o;
    }
}

// ---------------- LayerNorm: x (8192 x 1024) -> xn bf16 ----------------
__global__ __launch_bounds__(256) void ln_kernel(const float* __restrict__ x,
                                                 const float* __restrict__ g,
                                                 const float* __restrict__ b,
                                                 unsigned short* __restrict__ xn) {
    int row = blockIdx.x;
    int t = threadIdx.x;
    const float4* xr = (const float4*)(x + (size_t)row * D_MODEL);
    float4 v = xr[t];
    float s  = v.x + v.y + v.z + v.w;
    float ss = v.x * v.x + v.y * v.y + v.z * v.z + v.w * v.w;
    #pragma unroll
    for (int o = 32; o > 0; o >>= 1) {
        s  += __shfl_down(s,  o);
        ss += __shfl_down(ss, o);
    }
    __shared__ float sbuf[8];
    int wid = t >> 6;
    if ((t & 63) == 0) { sbuf[wid] = s; sbuf[4 + wid] = ss; }
    __syncthreads();
    float S  = sbuf[0] + sbuf[1] + sbuf[2] + sbuf[3];
    float SS = sbuf[4] + sbuf[5] + sbuf[6] + sbuf[7];
    float mu  = S * (1.0f / D_MODEL);
    float var = SS * (1.0f / D_MODEL) - mu * mu;
    float inv = rsqrtf(var + 1e-5f);
    float4 gv = ((const float4*)g)[t];
    float4 bv = ((const float4*)b)[t];
    ushort4 o;
    o.x = f2bf((v.x - mu) * inv * gv.x + bv.x);
    o.y = f2bf((v.y - mu) * inv * gv.y + bv.y);
    o.z = f2bf((v.z - mu) * inv * gv.z + bv.z);
    o.w = f2bf((v.w - mu) * inv * gv.w + bv.w);
    ((ushort4*)(xn + (size_t)row * D_MODEL))[t] = o;
}

// ---------------- GEMM1: 128x256 block, 4 waves of 64x128 ----------------
// Reg-prefetch + LDS double-buffer, ONE barrier per K-iter.
// D[m][n] = sum_k A[m][k]*Bt[n][k] + bias[n];  n<1024 -> u bf16; else silu -> zs
__global__ __launch_bounds__(256, 2) void gemm1_kernel(const unsigned short* __restrict__ A,
                                                       const unsigned short* __restrict__ Bt,
                                                       const float* __restrict__ bias,
                                                       unsigned short* __restrict__ u_bf,
                                                       unsigned short* __restrict__ zs) {
    __shared__ unsigned short lA[2][128 * 32];   // 8 KB x2
    __shared__ unsigned short lB[2][256 * 32];   // 16 KB x2
    const int K = D_MODEL;

    int t = threadIdx.x;
    int lane = t & 63;
    int wave = t >> 6;
    int wm = wave >> 1, wn = wave & 1;
    int m0 = blockIdx.y * 128;
    int n0 = blockIdx.x * 256;
    int row = lane & 15;
    int quad = lane >> 4;

    // staging: thread t owns 16B slot t in each 64-row half; fetch swizzled k-chunk
    int sr = t >> 2;
    int sc = ((t & 3) ^ ((t >> 3) & 3)) * 8;
    const unsigned short* gA0 = A + (size_t)(m0 + sr) * K + sc;
    const unsigned short* gA1 = A + (size_t)(m0 + 64 + sr) * K + sc;
    const unsigned short* gB0 = Bt + (size_t)(n0 + sr) * K + sc;
    const unsigned short* gB1 = Bt + (size_t)(n0 + 64 + sr) * K + sc;
    const unsigned short* gB2 = Bt + (size_t)(n0 + 128 + sr) * K + sc;
    const unsigned short* gB3 = Bt + (size_t)(n0 + 192 + sr) * K + sc;

    // fragment read offsets (swizzled)
    int offA[4], offB[8];
    #pragma unroll
    for (int i = 0; i < 4; i++) {
        int r6 = i * 16 + row;
        int slot = r6 * 4 + (quad ^ ((r6 >> 1) & 3));
        offA[i] = wm * 2048 + slot * 8;
    }
    #pragma unroll
    for (int j = 0; j < 8; j++) {
        int r8 = wn * 128 + j * 16 + row;
        int half = r8 >> 6, r6 = r8 & 63;
        int slot = r6 * 4 + (quad ^ ((r6 >> 1) & 3));
        offB[j] = half * 2048 + slot * 8;
    }

    // initial prefetch (k-chunk 0)
    u32x4 pa0 = *(const u32x4*)gA0;
    u32x4 pa1 = *(const u32x4*)gA1;
    u32x4 pb0 = *(const u32x4*)gB0;
    u32x4 pb1 = *(const u32x4*)gB1;
    u32x4 pb2 = *(const u32x4*)gB2;
    u32x4 pb3 = *(const u32x4*)gB3;

    f32x4 acc[4][8] = {};

    for (int kk = 0; kk < K; kk += 32) {
        int buf = (kk >> 5) & 1;
        unsigned short* sA = lA[buf];
        unsigned short* sB = lB[buf];
        // stage prefetched regs into LDS (compiler inserts vmcnt wait here)
        *(u32x4*)&sA[t * 8]        = pa0;
        *(u32x4*)&sA[2048 + t * 8] = pa1;
        *(u32x4*)&sB[t * 8]        = pb0;
        *(u32x4*)&sB[2048 + t * 8] = pb1;
        *(u32x4*)&sB[4096 + t * 8] = pb2;
        *(u32x4*)&sB[6144 + t * 8] = pb3;
        __syncthreads();   // only barrier this iter; no vm ops outstanding here
        // issue next-tile loads AFTER the barrier -> stay in flight across compute
        int kn = kk + 32;
        if (kn < K) {
            pa0 = *(const u32x4*)(gA0 + kn);
            pa1 = *(const u32x4*)(gA1 + kn);
            pb0 = *(const u32x4*)(gB0 + kn);
            pb1 = *(const u32x4*)(gB1 + kn);
            pb2 = *(const u32x4*)(gB2 + kn);
            pb3 = *(const u32x4*)(gB3 + kn);
        }
        short8 a[4];
        #pragma unroll
        for (int i = 0; i < 4; i++) a[i] = *(const short8*)&sA[offA[i]];
        #pragma unroll
        for (int j = 0; j < 8; j++) {
            short8 b = *(const short8*)&sB[offB[j]];
            #pragma unroll
            for (int i = 0; i < 4; i++)
                acc[i][j] = __builtin_amdgcn_mfma_f32_16x16x32_bf16(a[i], b, acc[i][j], 0, 0, 0);
        }
        // no trailing barrier: next iter writes the other LDS buffer
    }

    // epilogue: C/D layout col = lane&15, row = quad*4 + reg
    int col = row;
    #pragma unroll
    for (int j = 0; j < 8; j++) {
        int n = n0 + wn * 128 + j * 16 + col;
        float bs = bias[n];
        #pragma unroll
        for (int i = 0; i < 4; i++) {
            #pragma unroll
            for (int r = 0; r < 4; r++) {
                int m = m0 + wm * 64 + i * 16 + quad * 4 + r;
                float v = acc[i][j][r] + bs;
                if (n < D_MODEL) {
                    u_bf[(size_t)m * D_MODEL + n] = f2bf(v);
                } else {
                    float sv = v / (1.0f + __expf(-v));
                    zs[(size_t)m * D_MODEL + (n - D_MODEL)] = f2bf(sv);
                }
            }
        }
    }
}

// ---------------- GEMM2: 128x128 block, reg-prefetch + dbuf (resid+clip) ----------------
__global__ __launch_bounds__(256) void gemm2_kernel(const unsigned short* __restrict__ A,
                                                    const unsigned short* __restrict__ Bt,
                                                    const float* __restrict__ bias,
                                                    float* __restrict__ out_f,
                                                    const float* __restrict__ resid) {
    __shared__ unsigned short lA[2][128 * 32];   // 8 KB x2
    __shared__ unsigned short lB[2][128 * 32];   // 8 KB x2
    const int K = D_MODEL;

    int t = threadIdx.x;
    int lane = t & 63;
    int wave = t >> 6;
    int wm = wave >> 1, wn = wave & 1;
    int m0 = blockIdx.y * 128;
    int n0 = blockIdx.x * 128;
    int row = lane & 15;
    int quad = lane >> 4;

    int sr = t >> 2;
    int sc = ((t & 3) ^ ((t >> 3) & 3)) * 8;
    const unsigned short* gA0 = A + (size_t)(m0 + sr) * K + sc;
    const unsigned short* gA1 = A + (size_t)(m0 + 64 + sr) * K + sc;
    const unsigned short* gB0 = Bt + (size_t)(n0 + sr) * K + sc;
    const unsigned short* gB1 = Bt + (size_t)(n0 + 64 + sr) * K + sc;

    int offA[4], offB[4];
    #pragma unroll
    for (int i = 0; i < 4; i++) {
        int r6 = i * 16 + row;
        int slot = r6 * 4 + (quad ^ ((r6 >> 1) & 3));
        offA[i] = wm * 2048 + slot * 8;
        offB[i] = wn * 2048 + slot * 8;
    }

    u32x4 pa0 = *(const u32x4*)gA0;
    u32x4 pa1 = *(const u32x4*)gA1;
    u32x4 pb0 = *(const u32x4*)gB0;
    u32x4 pb1 = *(const u32x4*)gB1;

    f32x4 acc[4][4] = {};

    for (int kk = 0; kk < K; kk += 32) {
        int buf = (kk >> 5) & 1;
        unsigned short* sA = lA[buf];
        unsigned short* sB = lB[buf];
        *(u32x4*)&sA[t * 8]        = pa0;
        *(u32x4*)&sA[2048 + t * 8] = pa1;
        *(u32x4*)&sB[t * 8]        = pb0;
        *(u32x4*)&sB[2048 + t * 8] = pb1;
        __syncthreads();
        int kn = kk + 32;
        if (kn < K) {
            pa0 = *(const u32x4*)(gA0 + kn);
            pa1 = *(const u32x4*)(gA1 + kn);
            pb0 = *(const u32x4*)(gB0 + kn);
            pb1 = *(const u32x4*)(gB1 + kn);
        }
        short8 a[4], b[4];
        #pragma unroll
        for (int i = 0; i < 4; i++) a[i] = *(const short8*)&sA[offA[i]];
        #pragma unroll
        for (int j = 0; j < 4; j++) b[j] = *(const short8*)&sB[offB[j]];
        #pragma unroll
        for (int i = 0; i < 4; i++)
            #pragma unroll
            for (int j = 0; j < 4; j++)
                acc[i][j] = __builtin_amdgcn_mfma_f32_16x16x32_bf16(a[i], b[j], acc[i][j], 0, 0, 0);
    }

    int col = row;
    #pragma unroll
    for (int i = 0; i < 4; i++) {
        #pragma unroll
        for (int j = 0; j < 4; j++) {
            int n = n0 + wn * 64 + j * 16 + col;
            float bs = bias[n];
            #pragma unroll
            for (int r = 0; r < 4; r++) {
                int m = m0 + wm * 64 + i * 16 + quad * 4 + r;
                float y = acc[i][j][r] + bs + resid[(size_t)m * D_MODEL + n];
                y = fminf(10.0f, fmaxf(-10.0f, y));
                out_f[(size_t)m * D_MODEL + n] = y;
            }
        }
    }
}

// ---------------- chunked SSM scan (u bf16) ----------------
static __device__ __forceinline__ void load_params(const float* __restrict__ A_log,
                                                   const float* __restrict__ log_dt,
                                                   int d, float* ab, float& dt_out) {
    float dt = fminf(1.0f, fmaxf(1e-4f, __expf(log_dt[d])));
    #pragma unroll
    for (int n = 0; n < D_STATE; n++) {
        float a = __expf(-__expf(A_log[d * D_STATE + n]) * dt);
        ab[n] = fminf(1.0f - 1e-8f, fmaxf(1e-8f, a));
    }
    dt_out = dt;
}

// pass1: zero-init local scan of each chunk; writes chunk-final states.
__global__ __launch_bounds__(256) void scan1_kernel(const unsigned short* __restrict__ u,
                                                    const float* __restrict__ A_log,
                                                    const float* __restrict__ log_dt,
                                                    float* __restrict__ s_local) {
    int gid = blockIdx.x * 256 + threadIdx.x;
    int d = gid & (D_MODEL - 1);
    int c = (gid >> 10) & (N_CHUNK - 1);
    int b = gid >> 15;

    float ab[D_STATE], dt;
    load_params(A_log, log_dt, d, ab, dt);

    float s[D_STATE];
    #pragma unroll
    for (int n = 0; n < D_STATE; n++) s[n] = 0.0f;

    const unsigned short* up = u + ((size_t)(b * L_SEQ + c * C_LEN)) * D_MODEL + d;
    for (int t = 0; t < C_LEN; t++) {
        float uv = bf2f(up[(size_t)t * D_MODEL]);
        #pragma unroll
        for (int n = 0; n < D_STATE; n++) s[n] = fmaf(ab[n], s[n], uv);
    }
    float* sl = s_local + ((size_t)(b * N_CHUNK + c) * D_STATE) * D_MODEL + d;
    #pragma unroll
    for (int n = 0; n < D_STATE; n++) sl[(size_t)n * D_MODEL] = s[n];
}

// combine: sequential prefix over chunks.
__global__ __launch_bounds__(256) void scan_combine_kernel(const float* __restrict__ s_local,
                                                           const float* __restrict__ A_log,
                                                           const float* __restrict__ log_dt,
                                                           float* __restrict__ s_init) {
    int gid = blockIdx.x * 256 + threadIdx.x;
    int d = gid & (D_MODEL - 1);
    int n = (gid >> 10) & (D_STATE - 1);
    int b = gid >> 14;

    float dt = fminf(1.0f, fmaxf(1e-4f, __expf(log_dt[d])));
    float a = __expf(-__expf(A_log[d * D_STATE + n]) * dt);
    a = fminf(1.0f - 1e-8f, fmaxf(1e-8f, a));
    float aP = a;
    #pragma unroll
    for (int q = 0; q < 6; q++) aP = aP * aP;   // a^64

    float s = 0.0f;
    size_t stride_c = (size_t)D_STATE * D_MODEL;
    const float* sl = s_local + ((size_t)b * N_CHUNK * D_STATE + n) * D_MODEL + d;
    float* si = s_init + ((size_t)b * N_CHUNK * D_STATE + n) * D_MODEL + d;
    si[0] = 0.0f;
    for (int c = 1; c < N_CHUNK; c++) {
        s = fmaf(aP, s, sl[(size_t)(c - 1) * stride_c]);
        si[(size_t)c * stride_c] = s;
    }
}

// pass2: rescan with correct init; fuse y = sum_n cb_n s_n, y *= silu(z); bf16 out.
__global__ __launch_bounds__(256) void scan2_kernel(const unsigned short* __restrict__ u,
                                                    const unsigned short* __restrict__ zs,
                                                    const float* __restrict__ A_log,
                                                    const float* __restrict__ Bp,
                                                    const float* __restrict__ Cp,
                                                    const float* __restrict__ log_dt,
                                                    const float* __restrict__ s_init,
                                                    unsigned short* __restrict__ yz) {
    int gid = blockIdx.x * 256 + threadIdx.x;
    int d = gid & (D_MODEL - 1);
    int c = (gid >> 10) & (N_CHUNK - 1);
    int b = gid >> 15;

    float ab[D_STATE], dt;
    load_params(A_log, log_dt, d, ab, dt);
    float cb[D_STATE];
    #pragma unroll
    for (int n = 0; n < D_STATE; n++)
        cb[n] = Cp[d * D_STATE + n] * Bp[d * D_STATE + n] * dt;

    float s[D_STATE];
    const float* si = s_init + ((size_t)(b * N_CHUNK + c) * D_STATE) * D_MODEL + d;
    #pragma unroll
    for (int n = 0; n < D_STATE; n++) s[n] = si[(size_t)n * D_MODEL];

    size_t m0 = (size_t)(b * L_SEQ + c * C_LEN);
    const unsigned short* up = u + m0 * D_MODEL + d;
    const unsigned short* zp = zs + m0 * D_MODEL + d;
    unsigned short* yp = yz + m0 * D_MODEL + d;

    for (int t = 0; t < C_LEN; t++) {
        float uv = bf2f(up[(size_t)t * D_MODEL]);
        #pragma unroll
        for (int n = 0; n < D_STATE; n++) s[n] = fmaf(ab[n], s[n], uv);
        float y = 0.0f;
        #pragma unroll
        for (int n = 0; n < D_STATE; n++) y = fmaf(cb[n], s[n], y);
        float zv = bf2f(zp[(size_t)t * D_MODEL]);
        yp[(size_t)t * D_MODEL] = f2bf(y * zv);
    }
}

extern "C" void kernel_launch(void* const* d_in, const int* in_sizes, int n_in,
                              void* d_out, int out_size, void* d_ws, size_t ws_size,
                              hipStream_t stream) {
    const float* x       = (const float*)d_in[0];
    const float* A_log   = (const float*)d_in[1];
    const float* B_param = (const float*)d_in[2];
    const float* C_param = (const float*)d_in[3];
    const float* log_dt  = (const float*)d_in[4];
    const float* in_w    = (const float*)d_in[5];
    const float* in_b    = (const float*)d_in[6];
    const float* out_w   = (const float*)d_in[7];
    const float* out_b   = (const float*)d_in[8];
    const float* ln_g    = (const float*)d_in[9];
    const float* ln_b    = (const float*)d_in[10];
    float* out = (float*)d_out;

    char* ws = (char*)d_ws;
    size_t off = 0;
    unsigned short* xn = (unsigned short*)(ws + off); off += (size_t)M_ROWS * D_MODEL * 2;        // 16 MB
    unsigned short* w1 = (unsigned short*)(ws + off); off += (size_t)2 * D_MODEL * D_MODEL * 2;   // 4 MB
    unsigned short* u  = (unsigned short*)(ws + off); off += (size_t)M_ROWS * D_MODEL * 2;        // 16 MB
    unsigned short* zs = (unsigned short*)(ws + off); off += (size_t)M_ROWS * D_MODEL * 2;        // 16 MB
    unsigned short* yz = (unsigned short*)(ws + off); off += (size_t)M_ROWS * D_MODEL * 2;        // 16 MB
    unsigned short* w2 = (unsigned short*)(ws + off); off += (size_t)D_MODEL * D_MODEL * 2;       // 2 MB
    float* s_local = (float*)(ws + off); off += (size_t)B_SZ * N_CHUNK * D_STATE * D_MODEL * 4;   // 8 MB
    float* s_init  = (float*)(ws + off); off += (size_t)B_SZ * N_CHUNK * D_STATE * D_MODEL * 4;   // 8 MB

    // weights -> bf16
    {
        int n4 = 2 * D_MODEL * D_MODEL / 4;
        conv_bf16_kernel<<<(n4 + 255) / 256, 256, 0, stream>>>(in_w, w1, n4);
    }
    {
        int n4 = D_MODEL * D_MODEL / 4;
        conv_bf16_kernel<<<(n4 + 255) / 256, 256, 0, stream>>>(out_w, w2, n4);
    }

    // layernorm
    ln_kernel<<<M_ROWS, 256, 0, stream>>>(x, ln_g, ln_b, xn);

    // GEMM1: (8192x1024) @ (2048x1024)^T -> u bf16 / silu(z) bf16
    gemm1_kernel<<<dim3(2 * D_MODEL / 256, M_ROWS / 128), 256, 0, stream>>>(
        xn, w1, in_b, u, zs);

    // chunked SSM scan
    scan1_kernel<<<(B_SZ * N_CHUNK * D_MODEL) / 256, 256, 0, stream>>>(u, A_log, log_dt, s_local);
    scan_combine_kernel<<<(B_SZ * D_STATE * D_MODEL) / 256, 256, 0, stream>>>(s_local, A_log, log_dt, s_init);
    scan2_kernel<<<(B_SZ * N_CHUNK * D_MODEL) / 256, 256, 0, stream>>>(
        u, zs, A_log, B_param, C_param, log_dt, s_init, yz);

    // GEMM2: (8192x1024) @ (1024x1024)^T + resid, clip
    gemm2_kernel<<<dim3(D_MODEL / 128, M_ROWS / 128), 256, 0, stream>>>(
        yz, w2, out_b, out, x);
}

// Round 7
// 215.856 us; speedup vs baseline: 5.7893x; 1.0291x over previous
//
#include <hip/hip_runtime.h>
#include <hip/hip_bf16.h>

#define D_MODEL 1024
#define D_STATE 16
#define L_SEQ 2048
#define B_SZ 4
#define M_ROWS (B_SZ * L_SEQ)   // 8192
#define N_CHUNK 32               // chunks per sequence
#define C_LEN 64                 // timesteps per chunk (32*64 = 2048)

typedef __attribute__((ext_vector_type(8))) short short8;
typedef __attribute__((ext_vector_type(4))) float f32x4;
typedef unsigned int u32;
typedef __attribute__((ext_vector_type(4))) u32 u32x4;

// Raw workgroup barrier: drain LDS ops only (lgkmcnt), leave vmem loads in
// flight. __syncthreads would emit vmcnt(0) and kill the prefetch pipeline.
#define BAR() asm volatile("s_waitcnt lgkmcnt(0)\n\ts_barrier" ::: "memory")

static __device__ __forceinline__ unsigned short f2bf(float f) {
    unsigned int u = __float_as_uint(f);
    unsigned int r = (u + 0x7FFFu + ((u >> 16) & 1u)) >> 16;   // RNE
    return (unsigned short)r;
}
static __device__ __forceinline__ float bf2f(unsigned short u) {
    return __uint_as_float(((unsigned int)u) << 16);
}

// ---------------- convert fp32 -> bf16 (weights) ----------------
__global__ void conv_bf16_kernel(const float* __restrict__ src,
                                 unsigned short* __restrict__ dst, int n4) {
    int i = blockIdx.x * blockDim.x + threadIdx.x;
    if (i < n4) {
        float4 v = ((const float4*)src)[i];
        ushort4 o;
        o.x = f2bf(v.x); o.y = f2bf(v.y); o.z = f2bf(v.z); o.w = f2bf(v.w);
        ((ushort4*)dst)[i] = o;
    }
}

// ---------------- LayerNorm: x (8192 x 1024) -> xn bf16 ----------------
__global__ __launch_bounds__(256) void ln_kernel(const float* __restrict__ x,
                                                 const float* __restrict__ g,
                                                 const float* __restrict__ b,
                                                 unsigned short* __restrict__ xn) {
    int row = blockIdx.x;
    int t = threadIdx.x;
    const float4* xr = (const float4*)(x + (size_t)row * D_MODEL);
    float4 v = xr[t];
    float s  = v.x + v.y + v.z + v.w;
    float ss = v.x * v.x + v.y * v.y + v.z * v.z + v.w * v.w;
    #pragma unroll
    for (int o = 32; o > 0; o >>= 1) {
        s  += __shfl_down(s,  o);
        ss += __shfl_down(ss, o);
    }
    __shared__ float sbuf[8];
    int wid = t >> 6;
    if ((t & 63) == 0) { sbuf[wid] = s; sbuf[4 + wid] = ss; }
    __syncthreads();
    float S  = sbuf[0] + sbuf[1] + sbuf[2] + sbuf[3];
    float SS = sbuf[4] + sbuf[5] + sbuf[6] + sbuf[7];
    float mu  = S * (1.0f / D_MODEL);
    float var = SS * (1.0f / D_MODEL) - mu * mu;
    float inv = rsqrtf(var + 1e-5f);
    float4 gv = ((const float4*)g)[t];
    float4 bv = ((const float4*)b)[t];
    ushort4 o;
    o.x = f2bf((v.x - mu) * inv * gv.x + bv.x);
    o.y = f2bf((v.y - mu) * inv * gv.y + bv.y);
    o.z = f2bf((v.z - mu) * inv * gv.z + bv.z);
    o.w = f2bf((v.w - mu) * inv * gv.w + bv.w);
    ((ushort4*)(xn + (size_t)row * D_MODEL))[t] = o;
}

// ---------------- GEMM1: 128x256 block, 4 waves of 64x128 ----------------
// Reg-prefetch distance 2, LDS double-buffer, raw lgkm-only barrier.
// Grid: (x = row-block [64], y = col-block [8]) so all col-blocks sharing an
// A-panel have the same linear%8 -> same XCD -> A served from one L2.
__global__ __launch_bounds__(256, 2) void gemm1_kernel(const unsigned short* __restrict__ A,
                                                       const unsigned short* __restrict__ Bt,
                                                       const float* __restrict__ bias,
                                                       unsigned short* __restrict__ u_bf,
                                                       unsigned short* __restrict__ zs) {
    __shared__ unsigned short lA[2][128 * 32];   // 8 KB x2
    __shared__ unsigned short lB[2][256 * 32];   // 16 KB x2
    const int K = D_MODEL;

    int t = threadIdx.x;
    int lane = t & 63;
    int wave = t >> 6;
    int wm = wave >> 1, wn = wave & 1;
    int m0 = blockIdx.x * 128;
    int n0 = blockIdx.y * 256;
    int row = lane & 15;
    int quad = lane >> 4;

    // staging: thread t owns 16B slot t in each 64-row half; fetch swizzled k-chunk
    int sr = t >> 2;
    int sc = ((t & 3) ^ ((t >> 3) & 3)) * 8;
    const unsigned short* gA0 = A + (size_t)(m0 + sr) * K + sc;
    const unsigned short* gA1 = A + (size_t)(m0 + 64 + sr) * K + sc;
    const unsigned short* gB0 = Bt + (size_t)(n0 + sr) * K + sc;
    const unsigned short* gB1 = Bt + (size_t)(n0 + 64 + sr) * K + sc;
    const unsigned short* gB2 = Bt + (size_t)(n0 + 128 + sr) * K + sc;
    const unsigned short* gB3 = Bt + (size_t)(n0 + 192 + sr) * K + sc;

    // fragment read offsets (swizzled)
    int offA[4], offB[8];
    #pragma unroll
    for (int i = 0; i < 4; i++) {
        int r6 = i * 16 + row;
        int slot = r6 * 4 + (quad ^ ((r6 >> 1) & 3));
        offA[i] = wm * 2048 + slot * 8;
    }
    #pragma unroll
    for (int j = 0; j < 8; j++) {
        int r8 = wn * 128 + j * 16 + row;
        int half = r8 >> 6, r6 = r8 & 63;
        int slot = r6 * 4 + (quad ^ ((r6 >> 1) & 3));
        offB[j] = half * 2048 + slot * 8;
    }

    f32x4 acc[4][8] = {};

    // prefetch: PA <- k-chunk 0, PB <- k-chunk 32
    u32x4 PA[6], PB[6];
    PA[0] = *(const u32x4*)gA0;        PA[1] = *(const u32x4*)gA1;
    PA[2] = *(const u32x4*)gB0;        PA[3] = *(const u32x4*)gB1;
    PA[4] = *(const u32x4*)gB2;        PA[5] = *(const u32x4*)gB3;
    PB[0] = *(const u32x4*)(gA0 + 32); PB[1] = *(const u32x4*)(gA1 + 32);
    PB[2] = *(const u32x4*)(gB0 + 32); PB[3] = *(const u32x4*)(gB1 + 32);
    PB[4] = *(const u32x4*)(gB2 + 32); PB[5] = *(const u32x4*)(gB3 + 32);

    for (int kk = 0; kk < K; kk += 64) {
        // ---- half 0: buffer 0 holds k-chunk kk (from PA)
        *(u32x4*)&lA[0][t * 8]        = PA[0];
        *(u32x4*)&lA[0][2048 + t * 8] = PA[1];
        *(u32x4*)&lB[0][t * 8]        = PA[2];
        *(u32x4*)&lB[0][2048 + t * 8] = PA[3];
        *(u32x4*)&lB[0][4096 + t * 8] = PA[4];
        *(u32x4*)&lB[0][6144 + t * 8] = PA[5];
        if (kk + 64 < K) {
            int kn = kk + 64;
            PA[0] = *(const u32x4*)(gA0 + kn); PA[1] = *(const u32x4*)(gA1 + kn);
            PA[2] = *(const u32x4*)(gB0 + kn); PA[3] = *(const u32x4*)(gB1 + kn);
            PA[4] = *(const u32x4*)(gB2 + kn); PA[5] = *(const u32x4*)(gB3 + kn);
        }
        BAR();
        {
            short8 a[4];
            #pragma unroll
            for (int i = 0; i < 4; i++) a[i] = *(const short8*)&lA[0][offA[i]];
            #pragma unroll
            for (int j = 0; j < 8; j++) {
                short8 b = *(const short8*)&lB[0][offB[j]];
                #pragma unroll
                for (int i = 0; i < 4; i++)
                    acc[i][j] = __builtin_amdgcn_mfma_f32_16x16x32_bf16(a[i], b, acc[i][j], 0, 0, 0);
            }
        }
        // ---- half 1: buffer 1 holds k-chunk kk+32 (from PB)
        *(u32x4*)&lA[1][t * 8]        = PB[0];
        *(u32x4*)&lA[1][2048 + t * 8] = PB[1];
        *(u32x4*)&lB[1][t * 8]        = PB[2];
        *(u32x4*)&lB[1][2048 + t * 8] = PB[3];
        *(u32x4*)&lB[1][4096 + t * 8] = PB[4];
        *(u32x4*)&lB[1][6144 + t * 8] = PB[5];
        if (kk + 96 < K) {
            int kn = kk + 96;
            PB[0] = *(const u32x4*)(gA0 + kn); PB[1] = *(const u32x4*)(gA1 + kn);
            PB[2] = *(const u32x4*)(gB0 + kn); PB[3] = *(const u32x4*)(gB1 + kn);
            PB[4] = *(const u32x4*)(gB2 + kn); PB[5] = *(const u32x4*)(gB3 + kn);
        }
        BAR();
        {
            short8 a[4];
            #pragma unroll
            for (int i = 0; i < 4; i++) a[i] = *(const short8*)&lA[1][offA[i]];
            #pragma unroll
            for (int j = 0; j < 8; j++) {
                short8 b = *(const short8*)&lB[1][offB[j]];
                #pragma unroll
                for (int i = 0; i < 4; i++)
                    acc[i][j] = __builtin_amdgcn_mfma_f32_16x16x32_bf16(a[i], b, acc[i][j], 0, 0, 0);
            }
        }
    }

    // epilogue: C/D layout col = lane&15, row = quad*4 + reg
    int col = row;
    #pragma unroll
    for (int j = 0; j < 8; j++) {
        int n = n0 + wn * 128 + j * 16 + col;
        float bs = bias[n];
        #pragma unroll
        for (int i = 0; i < 4; i++) {
            #pragma unroll
            for (int r = 0; r < 4; r++) {
                int m = m0 + wm * 64 + i * 16 + quad * 4 + r;
                float v = acc[i][j][r] + bs;
                if (n < D_MODEL) {
                    u_bf[(size_t)m * D_MODEL + n] = f2bf(v);
                } else {
                    float sv = v / (1.0f + __expf(-v));
                    zs[(size_t)m * D_MODEL + (n - D_MODEL)] = f2bf(sv);
                }
            }
        }
    }
}

// ---------------- GEMM2: 128x128 block, prefetch-2 + dbuf + raw barrier ----------------
// Grid: (x = row-block [64], y = col-block [8]) — same XCD swizzle as gemm1.
__global__ __launch_bounds__(256) void gemm2_kernel(const unsigned short* __restrict__ A,
                                                    const unsigned short* __restrict__ Bt,
                                                    const float* __restrict__ bias,
                                                    float* __restrict__ out_f,
                                                    const float* __restrict__ resid) {
    __shared__ unsigned short lA[2][128 * 32];   // 8 KB x2
    __shared__ unsigned short lB[2][128 * 32];   // 8 KB x2
    const int K = D_MODEL;

    int t = threadIdx.x;
    int lane = t & 63;
    int wave = t >> 6;
    int wm = wave >> 1, wn = wave & 1;
    int m0 = blockIdx.x * 128;
    int n0 = blockIdx.y * 128;
    int row = lane & 15;
    int quad = lane >> 4;

    int sr = t >> 2;
    int sc = ((t & 3) ^ ((t >> 3) & 3)) * 8;
    const unsigned short* gA0 = A + (size_t)(m0 + sr) * K + sc;
    const unsigned short* gA1 = A + (size_t)(m0 + 64 + sr) * K + sc;
    const unsigned short* gB0 = Bt + (size_t)(n0 + sr) * K + sc;
    const unsigned short* gB1 = Bt + (size_t)(n0 + 64 + sr) * K + sc;

    int offA[4], offB[4];
    #pragma unroll
    for (int i = 0; i < 4; i++) {
        int r6 = i * 16 + row;
        int slot = r6 * 4 + (quad ^ ((r6 >> 1) & 3));
        offA[i] = wm * 2048 + slot * 8;
        offB[i] = wn * 2048 + slot * 8;
    }

    f32x4 acc[4][4] = {};

    u32x4 PA[4], PB[4];
    PA[0] = *(const u32x4*)gA0;        PA[1] = *(const u32x4*)gA1;
    PA[2] = *(const u32x4*)gB0;        PA[3] = *(const u32x4*)gB1;
    PB[0] = *(const u32x4*)(gA0 + 32); PB[1] = *(const u32x4*)(gA1 + 32);
    PB[2] = *(const u32x4*)(gB0 + 32); PB[3] = *(const u32x4*)(gB1 + 32);

    for (int kk = 0; kk < K; kk += 64) {
        // half 0
        *(u32x4*)&lA[0][t * 8]        = PA[0];
        *(u32x4*)&lA[0][2048 + t * 8] = PA[1];
        *(u32x4*)&lB[0][t * 8]        = PA[2];
        *(u32x4*)&lB[0][2048 + t * 8] = PA[3];
        if (kk + 64 < K) {
            int kn = kk + 64;
            PA[0] = *(const u32x4*)(gA0 + kn); PA[1] = *(const u32x4*)(gA1 + kn);
            PA[2] = *(const u32x4*)(gB0 + kn); PA[3] = *(const u32x4*)(gB1 + kn);
        }
        BAR();
        {
            short8 a[4], b[4];
            #pragma unroll
            for (int i = 0; i < 4; i++) a[i] = *(const short8*)&lA[0][offA[i]];
            #pragma unroll
            for (int j = 0; j < 4; j++) b[j] = *(const short8*)&lB[0][offB[j]];
            #pragma unroll
            for (int i = 0; i < 4; i++)
                #pragma unroll
                for (int j = 0; j < 4; j++)
                    acc[i][j] = __builtin_amdgcn_mfma_f32_16x16x32_bf16(a[i], b[j], acc[i][j], 0, 0, 0);
        }
        // half 1
        *(u32x4*)&lA[1][t * 8]        = PB[0];
        *(u32x4*)&lA[1][2048 + t * 8] = PB[1];
        *(u32x4*)&lB[1][t * 8]        = PB[2];
        *(u32x4*)&lB[1][2048 + t * 8] = PB[3];
        if (kk + 96 < K) {
            int kn = kk + 96;
            PB[0] = *(const u32x4*)(gA0 + kn); PB[1] = *(const u32x4*)(gA1 + kn);
            PB[2] = *(const u32x4*)(gB0 + kn); PB[3] = *(const u32x4*)(gB1 + kn);
        }
        BAR();
        {
            short8 a[4], b[4];
            #pragma unroll
            for (int i = 0; i < 4; i++) a[i] = *(const short8*)&lA[1][offA[i]];
            #pragma unroll
            for (int j = 0; j < 4; j++) b[j] = *(const short8*)&lB[1][offB[j]];
            #pragma unroll
            for (int i = 0; i < 4; i++)
                #pragma unroll
                for (int j = 0; j < 4; j++)
                    acc[i][j] = __builtin_amdgcn_mfma_f32_16x16x32_bf16(a[i], b[j], acc[i][j], 0, 0, 0);
        }
    }

    int col = row;
    #pragma unroll
    for (int i = 0; i < 4; i++) {
        #pragma unroll
        for (int j = 0; j < 4; j++) {
            int n = n0 + wn * 64 + j * 16 + col;
            float bs = bias[n];
            #pragma unroll
            for (int r = 0; r < 4; r++) {
                int m = m0 + wm * 64 + i * 16 + quad * 4 + r;
                float y = acc[i][j][r] + bs + resid[(size_t)m * D_MODEL + n];
                y = fminf(10.0f, fmaxf(-10.0f, y));
                out_f[(size_t)m * D_MODEL + n] = y;
            }
        }
    }
}

// ---------------- chunked SSM scan (u bf16) ----------------
static __device__ __forceinline__ void load_params(const float* __restrict__ A_log,
                                                   const float* __restrict__ log_dt,
                                                   int d, float* ab, float& dt_out) {
    float dt = fminf(1.0f, fmaxf(1e-4f, __expf(log_dt[d])));
    #pragma unroll
    for (int n = 0; n < D_STATE; n++) {
        float a = __expf(-__expf(A_log[d * D_STATE + n]) * dt);
        ab[n] = fminf(1.0f - 1e-8f, fmaxf(1e-8f, a));
    }
    dt_out = dt;
}

// pass1: zero-init local scan of each chunk; writes chunk-final states.
__global__ __launch_bounds__(256) void scan1_kernel(const unsigned short* __restrict__ u,
                                                    const float* __restrict__ A_log,
                                                    const float* __restrict__ log_dt,
                                                    float* __restrict__ s_local) {
    int gid = blockIdx.x * 256 + threadIdx.x;
    int d = gid & (D_MODEL - 1);
    int c = (gid >> 10) & (N_CHUNK - 1);
    int b = gid >> 15;

    float ab[D_STATE], dt;
    load_params(A_log, log_dt, d, ab, dt);

    float s[D_STATE];
    #pragma unroll
    for (int n = 0; n < D_STATE; n++) s[n] = 0.0f;

    const unsigned short* up = u + ((size_t)(b * L_SEQ + c * C_LEN)) * D_MODEL + d;
    for (int t = 0; t < C_LEN; t++) {
        float uv = bf2f(up[(size_t)t * D_MODEL]);
        #pragma unroll
        for (int n = 0; n < D_STATE; n++) s[n] = fmaf(ab[n], s[n], uv);
    }
    float* sl = s_local + ((size_t)(b * N_CHUNK + c) * D_STATE) * D_MODEL + d;
    #pragma unroll
    for (int n = 0; n < D_STATE; n++) sl[(size_t)n * D_MODEL] = s[n];
}

// combine: sequential prefix over chunks.
__global__ __launch_bounds__(256) void scan_combine_kernel(const float* __restrict__ s_local,
                                                           const float* __restrict__ A_log,
                                                           const float* __restrict__ log_dt,
                                                           float* __restrict__ s_init) {
    int gid = blockIdx.x * 256 + threadIdx.x;
    int d = gid & (D_MODEL - 1);
    int n = (gid >> 10) & (D_STATE - 1);
    int b = gid >> 14;

    float dt = fminf(1.0f, fmaxf(1e-4f, __expf(log_dt[d])));
    float a = __expf(-__expf(A_log[d * D_STATE + n]) * dt);
    a = fminf(1.0f - 1e-8f, fmaxf(1e-8f, a));
    float aP = a;
    #pragma unroll
    for (int q = 0; q < 6; q++) aP = aP * aP;   // a^64

    float s = 0.0f;
    size_t stride_c = (size_t)D_STATE * D_MODEL;
    const float* sl = s_local + ((size_t)b * N_CHUNK * D_STATE + n) * D_MODEL + d;
    float* si = s_init + ((size_t)b * N_CHUNK * D_STATE + n) * D_MODEL + d;
    si[0] = 0.0f;
    for (int c = 1; c < N_CHUNK; c++) {
        s = fmaf(aP, s, sl[(size_t)(c - 1) * stride_c]);
        si[(size_t)c * stride_c] = s;
    }
}

// pass2: rescan with correct init; fuse y = sum_n cb_n s_n, y *= silu(z); bf16 out.
__global__ __launch_bounds__(256) void scan2_kernel(const unsigned short* __restrict__ u,
                                                    const unsigned short* __restrict__ zs,
                                                    const float* __restrict__ A_log,
                                                    const float* __restrict__ Bp,
                                                    const float* __restrict__ Cp,
                                                    const float* __restrict__ log_dt,
                                                    const float* __restrict__ s_init,
                                                    unsigned short* __restrict__ yz) {
    int gid = blockIdx.x * 256 + threadIdx.x;
    int d = gid & (D_MODEL - 1);
    int c = (gid >> 10) & (N_CHUNK - 1);
    int b = gid >> 15;

    float ab[D_STATE], dt;
    load_params(A_log, log_dt, d, ab, dt);
    float cb[D_STATE];
    #pragma unroll
    for (int n = 0; n < D_STATE; n++)
        cb[n] = Cp[d * D_STATE + n] * Bp[d * D_STATE + n] * dt;

    float s[D_STATE];
    const float* si = s_init + ((size_t)(b * N_CHUNK + c) * D_STATE) * D_MODEL + d;
    #pragma unroll
    for (int n = 0; n < D_STATE; n++) s[n] = si[(size_t)n * D_MODEL];

    size_t m0 = (size_t)(b * L_SEQ + c * C_LEN);
    const unsigned short* up = u + m0 * D_MODEL + d;
    const unsigned short* zp = zs + m0 * D_MODEL + d;
    unsigned short* yp = yz + m0 * D_MODEL + d;

    for (int t = 0; t < C_LEN; t++) {
        float uv = bf2f(up[(size_t)t * D_MODEL]);
        #pragma unroll
        for (int n = 0; n < D_STATE; n++) s[n] = fmaf(ab[n], s[n], uv);
        float y = 0.0f;
        #pragma unroll
        for (int n = 0; n < D_STATE; n++) y = fmaf(cb[n], s[n], y);
        float zv = bf2f(zp[(size_t)t * D_MODEL]);
        yp[(size_t)t * D_MODEL] = f2bf(y * zv);
    }
}

extern "C" void kernel_launch(void* const* d_in, const int* in_sizes, int n_in,
                              void* d_out, int out_size, void* d_ws, size_t ws_size,
                              hipStream_t stream) {
    const float* x       = (const float*)d_in[0];
    const float* A_log   = (const float*)d_in[1];
    const float* B_param = (const float*)d_in[2];
    const float* C_param = (const float*)d_in[3];
    const float* log_dt  = (const float*)d_in[4];
    const float* in_w    = (const float*)d_in[5];
    const float* in_b    = (const float*)d_in[6];
    const float* out_w   = (const float*)d_in[7];
    const float* out_b   = (const float*)d_in[8];
    const float* ln_g    = (const float*)d_in[9];
    const float* ln_b    = (const float*)d_in[10];
    float* out = (float*)d_out;

    char* ws = (char*)d_ws;
    size_t off = 0;
    unsigned short* xn = (unsigned short*)(ws + off); off += (size_t)M_ROWS * D_MODEL * 2;        // 16 MB
    unsigned short* w1 = (unsigned short*)(ws + off); off += (size_t)2 * D_MODEL * D_MODEL * 2;   // 4 MB
    unsigned short* u  = (unsigned short*)(ws + off); off += (size_t)M_ROWS * D_MODEL * 2;        // 16 MB
    unsigned short* zs = (unsigned short*)(ws + off); off += (size_t)M_ROWS * D_MODEL * 2;        // 16 MB
    unsigned short* yz = (unsigned short*)(ws + off); off += (size_t)M_ROWS * D_MODEL * 2;        // 16 MB
    unsigned short* w2 = (unsigned short*)(ws + off); off += (size_t)D_MODEL * D_MODEL * 2;       // 2 MB
    float* s_local = (float*)(ws + off); off += (size_t)B_SZ * N_CHUNK * D_STATE * D_MODEL * 4;   // 8 MB
    float* s_init  = (float*)(ws + off); off += (size_t)B_SZ * N_CHUNK * D_STATE * D_MODEL * 4;   // 8 MB

    // weights -> bf16
    {
        int n4 = 2 * D_MODEL * D_MODEL / 4;
        conv_bf16_kernel<<<(n4 + 255) / 256, 256, 0, stream>>>(in_w, w1, n4);
    }
    {
        int n4 = D_MODEL * D_MODEL / 4;
        conv_bf16_kernel<<<(n4 + 255) / 256, 256, 0, stream>>>(out_w, w2, n4);
    }

    // layernorm
    ln_kernel<<<M_ROWS, 256, 0, stream>>>(x, ln_g, ln_b, xn);

    // GEMM1: (8192x1024) @ (2048x1024)^T -> u bf16 / silu(z) bf16
    gemm1_kernel<<<dim3(M_ROWS / 128, 2 * D_MODEL / 256), 256, 0, stream>>>(
        xn, w1, in_b, u, zs);

    // chunked SSM scan
    scan1_kernel<<<(B_SZ * N_CHUNK * D_MODEL) / 256, 256, 0, stream>>>(u, A_log, log_dt, s_local);
    scan_combine_kernel<<<(B_SZ * D_STATE * D_MODEL) / 256, 256, 0, stream>>>(s_local, A_log, log_dt, s_init);
    scan2_kernel<<<(B_SZ * N_CHUNK * D_MODEL) / 256, 256, 0, stream>>>(
        u, zs, A_log, B_param, C_param, log_dt, s_init, yz);

    // GEMM2: (8192x1024) @ (1024x1024)^T + resid, clip
    gemm2_kernel<<<dim3(M_ROWS / 128, D_MODEL / 128), 256, 0, stream>>>(
        yz, w2, out_b, out, x);
}